// Round 1
// baseline (626.988 us; speedup 1.0000x reference)
//
#include <hip/hip_runtime.h>
#include <math.h>

#define B_ 8
#define S_ 1024
#define DIM_ 192
#define INNER_ 288
#define NHM_ 4
#define DHM_ 72
#define H_ 32
#define W_ 32

// ---------------- GEMM: C[M,N] = A[M,K] * B[N,K]^T (all row-major fp32) ----
__global__ __launch_bounds__(256) void gemm_bt(
    const float* __restrict__ A, const float* __restrict__ Bm,
    float* __restrict__ C, int M, int N, int K) {
  __shared__ float As[16][68];
  __shared__ float Bs[16][68];
  const int m0 = blockIdx.y * 64, n0 = blockIdx.x * 64;
  const int tid = threadIdx.x;
  const int tx = tid & 15, ty = tid >> 4;
  const int lr = tid >> 2;          // 0..63
  const int lk = (tid & 3) << 2;    // 0,4,8,12
  float acc[4][4] = {};
  for (int k0 = 0; k0 < K; k0 += 16) {
    const float4 av = *reinterpret_cast<const float4*>(&A[(size_t)(m0 + lr) * K + k0 + lk]);
    const float4 bv = *reinterpret_cast<const float4*>(&Bm[(size_t)(n0 + lr) * K + k0 + lk]);
    __syncthreads();
    As[lk + 0][lr] = av.x; As[lk + 1][lr] = av.y; As[lk + 2][lr] = av.z; As[lk + 3][lr] = av.w;
    Bs[lk + 0][lr] = bv.x; Bs[lk + 1][lr] = bv.y; Bs[lk + 2][lr] = bv.z; Bs[lk + 3][lr] = bv.w;
    __syncthreads();
#pragma unroll
    for (int kk = 0; kk < 16; ++kk) {
      const float4 a4 = *reinterpret_cast<const float4*>(&As[kk][ty * 4]);
      const float4 b4 = *reinterpret_cast<const float4*>(&Bs[kk][tx * 4]);
      const float a[4] = {a4.x, a4.y, a4.z, a4.w};
      const float b[4] = {b4.x, b4.y, b4.z, b4.w};
#pragma unroll
      for (int i = 0; i < 4; ++i)
#pragma unroll
        for (int j = 0; j < 4; ++j) acc[i][j] += a[i] * b[j];
    }
  }
#pragma unroll
  for (int i = 0; i < 4; ++i) {
    const size_t m = (size_t)m0 + ty * 4 + i;
    float4 o; o.x = acc[i][0]; o.y = acc[i][1]; o.z = acc[i][2]; o.w = acc[i][3];
    *reinterpret_cast<float4*>(&C[m * N + n0 + tx * 4]) = o;
  }
}

// ---------------- depthwise 3x3 conv (SAME) + SiLU -------------------------
__global__ __launch_bounds__(256) void conv_silu_kernel(
    const float* __restrict__ y, const float* __restrict__ cw, float* __restrict__ xa) {
  const int idx = blockIdx.x * 256 + threadIdx.x;   // over B*S*INNER
  const int c = idx % INNER_;
  const int p = idx / INNER_;                       // b*S + s
  const int xx = p & 31, yy = (p >> 5) & 31, b = p >> 10;
  float acc = 0.f;
#pragma unroll
  for (int ky = 0; ky < 3; ++ky) {
    const int iy = yy + ky - 1;
    if (iy < 0 || iy >= H_) continue;
#pragma unroll
    for (int kx = 0; kx < 3; ++kx) {
      const int ix = xx + kx - 1;
      if (ix < 0 || ix >= W_) continue;
      acc += y[((size_t)((b << 10) + (iy << 5) + ix)) * 576 + c] * cw[(ky * 3 + kx) * INNER_ + c];
    }
  }
  xa[(size_t)p * INNER_ + c] = acc / (1.f + expf(-acc));
}

// ---------------- headwise q/k/v (72 heads x 4x4) --------------------------
// writes q,k,v directly in mLSTM head layout: [b][n][s][d], n=c/72, d=c%72
__global__ __launch_bounds__(256) void headwise_kernel(
    const float* __restrict__ y, const float* __restrict__ xa,
    const float* __restrict__ qw, const float* __restrict__ kw, const float* __restrict__ vw,
    float* __restrict__ qh, float* __restrict__ kh, float* __restrict__ vh) {
  const int idx = blockIdx.x * 256 + threadIdx.x;   // over B*S*INNER
  const int c = idx % INNER_;
  const int p = idx / INNER_;
  const int b = p >> 10, s = p & 1023;
  const int hq = c >> 2, o = c & 3;
  const float* xav = &xa[(size_t)p * INNER_ + (hq << 2)];
  const float* xmv = &y[(size_t)p * 576 + (hq << 2)];   // x_m = y[:, :288]
  float q = 0.f, k = 0.f, v = 0.f;
#pragma unroll
  for (int d = 0; d < 4; ++d) {
    const int wi = hq * 16 + o * 4 + d;
    q += qw[wi] * xav[d];
    k += kw[wi] * xav[d];
    v += vw[wi] * xmv[d];
  }
  const int n = c / DHM_, dd = c % DHM_;
  const size_t oi = (((size_t)b * NHM_ + n) * S_ + s) * DHM_ + dd;
  qh[oi] = q; kh[oi] = k; vh[oi] = v;
}

// ---------------- gates: ig/fg = [q,k,v] @ w^T + b, layout [b][n][s] -------
__global__ __launch_bounds__(256) void gates_kernel(
    const float* __restrict__ qh, const float* __restrict__ kh, const float* __restrict__ vh,
    const float* __restrict__ igw, const float* __restrict__ igb,
    const float* __restrict__ fgw, const float* __restrict__ fgb,
    float* __restrict__ ig, float* __restrict__ fg) {
  const int gw = (blockIdx.x * 256 + threadIdx.x) >> 6;  // wave id = b*S+s
  const int lane = threadIdx.x & 63;
  const int b = gw >> 10, s = gw & 1023;
  float iacc[4] = {}, facc[4] = {};
  for (int j = lane; j < 864; j += 64) {
    const int part = j / INNER_;
    const int c = j - part * INNER_;
    const int n = c / DHM_, d = c % DHM_;
    const size_t idx = (((size_t)b * NHM_ + n) * S_ + s) * DHM_ + d;
    const float gv = (part == 0) ? qh[idx] : ((part == 1) ? kh[idx] : vh[idx]);
#pragma unroll
    for (int nn = 0; nn < 4; ++nn) {
      iacc[nn] += gv * igw[nn * 864 + j];
      facc[nn] += gv * fgw[nn * 864 + j];
    }
  }
#pragma unroll
  for (int off = 32; off >= 1; off >>= 1) {
#pragma unroll
    for (int nn = 0; nn < 4; ++nn) {
      iacc[nn] += __shfl_xor(iacc[nn], off);
      facc[nn] += __shfl_xor(facc[nn], off);
    }
  }
  if (lane == 0) {
#pragma unroll
    for (int nn = 0; nn < 4; ++nn) {
      ig[((size_t)b * NHM_ + nn) * S_ + s] = iacc[nn] + igb[nn];
      fg[((size_t)b * NHM_ + nn) * S_ + s] = facc[nn] + fgb[nn];
    }
  }
}

// ---------------- per-(b,n) scans: lfc = cumsum(logsigmoid(fg)); -----------
// g = ig - lfc; M = prefix-max(g)
__global__ __launch_bounds__(256) void scan_kernel(
    const float* __restrict__ fg, const float* __restrict__ ig,
    float* __restrict__ lfc, float* __restrict__ g, float* __restrict__ Mb) {
  __shared__ float sd[256];
  const int bn = blockIdx.x;   // 0..B*NHM-1
  const int tid = threadIdx.x;
  const float* fgp = &fg[(size_t)bn * S_];
  const float* igp = &ig[(size_t)bn * S_];
  float lf[4];
#pragma unroll
  for (int i = 0; i < 4; ++i) {
    const float f = fgp[tid * 4 + i];
    lf[i] = (f >= 0.f) ? -log1pf(expf(-f)) : (f - log1pf(expf(f)));
  }
  float p[4];
  p[0] = lf[0]; p[1] = p[0] + lf[1]; p[2] = p[1] + lf[2]; p[3] = p[2] + lf[3];
  sd[tid] = p[3];
  __syncthreads();
  for (int off = 1; off < 256; off <<= 1) {
    const float v = (tid >= off) ? sd[tid - off] : 0.f;
    __syncthreads();
    sd[tid] += v;
    __syncthreads();
  }
  const float excl = sd[tid] - p[3];
  float l[4];
#pragma unroll
  for (int i = 0; i < 4; ++i) {
    l[i] = excl + p[i];
    lfc[(size_t)bn * S_ + tid * 4 + i] = l[i];
  }
  // prefix max of g
  float gv[4], pm[4];
#pragma unroll
  for (int i = 0; i < 4; ++i) gv[i] = igp[tid * 4 + i] - l[i];
  pm[0] = gv[0];
#pragma unroll
  for (int i = 1; i < 4; ++i) pm[i] = fmaxf(pm[i - 1], gv[i]);
  __syncthreads();
  sd[tid] = pm[3];
  __syncthreads();
  for (int off = 1; off < 256; off <<= 1) {
    const float v = (tid >= off) ? sd[tid - off] : -INFINITY;
    __syncthreads();
    sd[tid] = fmaxf(sd[tid], v);
    __syncthreads();
  }
  const float exclm = (tid > 0) ? sd[tid - 1] : -INFINITY;
#pragma unroll
  for (int i = 0; i < 4; ++i) {
    g[(size_t)bn * S_ + tid * 4 + i] = gv[i];
    Mb[(size_t)bn * S_ + tid * 4 + i] = fmaxf(exclm, pm[i]);
  }
}

// ---------------- mLSTM core: per (b,n,s-tile of 64) -----------------------
// h[s,:] = (sum_t qk[s,t]*exp(g[t]-M[s]) * v[t]) / (max(|rowsum|,exp(-(lfc+M)))+eps)
__global__ __launch_bounds__(256) void mlstm_kernel(
    const float* __restrict__ qh, const float* __restrict__ kh, const float* __restrict__ vh,
    const float* __restrict__ gb, const float* __restrict__ Mb, const float* __restrict__ lfc,
    float* __restrict__ h) {
  __shared__ float Qs[64][76];
  __shared__ float Ks[64][76];
  __shared__ float VsT[73][68];   // VsT[c][t]; row 72 = ones (rowsum column)
  __shared__ float Ws[64][68];
  __shared__ float Ms_s[64], en_s[64], gs[64], rs_s[64];
  const int tid = threadIdx.x;
  const int st = blockIdx.x & 15;
  const int bn = blockIdx.x >> 4;
  const int s0 = st << 6;
  const float* qp = qh + (size_t)bn * S_ * DHM_;
  const float* kp = kh + (size_t)bn * S_ * DHM_;
  const float* vp = vh + (size_t)bn * S_ * DHM_;
  // load Q tile (64x72) vectorized
  for (int i = tid; i < 64 * 18; i += 256) {
    const int r = i / 18, d4 = (i % 18) * 4;
    *reinterpret_cast<float4*>(&Qs[r][d4]) =
        *reinterpret_cast<const float4*>(&qp[(size_t)(s0 + r) * DHM_ + d4]);
  }
  if (tid < 64) {
    const int sg = s0 + tid;
    const float m = Mb[(size_t)bn * S_ + sg];
    Ms_s[tid] = m;
    en_s[tid] = expf(-(lfc[(size_t)bn * S_ + sg] + m));
  }
  float acc[4][5] = {};
  const int tx = tid & 15, ty = tid >> 4;
  const float rsc = 0.11785113019775793f;   // 1/sqrt(72)
  for (int tt = 0; tt <= st; ++tt) {
    const int t0 = tt << 6;
    __syncthreads();   // previous PV done before overwriting K/V/W
    for (int i = tid; i < 64 * 18; i += 256) {
      const int r = i / 18, d4 = (i % 18) * 4;
      *reinterpret_cast<float4*>(&Ks[r][d4]) =
          *reinterpret_cast<const float4*>(&kp[(size_t)(t0 + r) * DHM_ + d4]);
      const float4 vv = *reinterpret_cast<const float4*>(&vp[(size_t)(t0 + r) * DHM_ + d4]);
      VsT[d4 + 0][r] = vv.x; VsT[d4 + 1][r] = vv.y; VsT[d4 + 2][r] = vv.z; VsT[d4 + 3][r] = vv.w;
    }
    if (tid < 64) { VsT[72][tid] = 1.f; gs[tid] = gb[(size_t)bn * S_ + t0 + tid]; }
    __syncthreads();
    // QK^T: each thread 4x4
    float qk[4][4] = {};
    for (int d = 0; d < DHM_; d += 4) {
      float4 ar[4], br[4];
#pragma unroll
      for (int i = 0; i < 4; ++i) ar[i] = *reinterpret_cast<const float4*>(&Qs[ty + 16 * i][d]);
#pragma unroll
      for (int j = 0; j < 4; ++j) br[j] = *reinterpret_cast<const float4*>(&Ks[tx + 16 * j][d]);
#pragma unroll
      for (int i = 0; i < 4; ++i)
#pragma unroll
        for (int j = 0; j < 4; ++j)
          qk[i][j] += ar[i].x * br[j].x + ar[i].y * br[j].y + ar[i].z * br[j].z + ar[i].w * br[j].w;
    }
    // decay weight + causal mask
#pragma unroll
    for (int i = 0; i < 4; ++i) {
      const int sr = ty + 16 * i;
      const int sg = s0 + sr;
      const float m = Ms_s[sr];
#pragma unroll
      for (int j = 0; j < 4; ++j) {
        const int tc = tx + 16 * j;
        const int tg = t0 + tc;
        float w = 0.f;
        if (tg <= sg) w = qk[i][j] * rsc * expf(gs[tc] - m);
        Ws[sr][tc] = w;
      }
    }
    __syncthreads();
    // PV: acc[4][5] covers 72 dims + rowsum col (72)
    for (int t = 0; t < 64; t += 4) {
      float4 wv[4];
#pragma unroll
      for (int i = 0; i < 4; ++i) wv[i] = *reinterpret_cast<const float4*>(&Ws[ty + 16 * i][t]);
#pragma unroll
      for (int j = 0; j < 5; ++j) {
        const int cc = tx + 16 * j;
        if (cc <= 72) {
          const float4 vt = *reinterpret_cast<const float4*>(&VsT[cc][t]);
#pragma unroll
          for (int i = 0; i < 4; ++i)
            acc[i][j] += wv[i].x * vt.x + wv[i].y * vt.y + wv[i].z * vt.z + wv[i].w * vt.w;
        }
      }
    }
  }
  __syncthreads();
  if (tx == 8) {
#pragma unroll
    for (int i = 0; i < 4; ++i) rs_s[ty + 16 * i] = acc[i][4];
  }
  __syncthreads();
#pragma unroll
  for (int i = 0; i < 4; ++i) {
    const int sr = ty + 16 * i;
    const float norm = fmaxf(fabsf(rs_s[sr]), en_s[sr]) + 1e-6f;
    const float inv = 1.f / norm;
#pragma unroll
    for (int j = 0; j < 5; ++j) {
      const int cc = tx + 16 * j;
      if (cc < 72) h[((size_t)bn * S_ + (s0 + sr)) * DHM_ + cc] = acc[i][j] * inv;
    }
  }
}

// ---------------- headwise LN + skip + silu(z) gate ------------------------
__global__ __launch_bounds__(256) void ln_fuse_kernel(
    const float* __restrict__ hb, const float* __restrict__ xa, const float* __restrict__ y,
    const float* __restrict__ normw, const float* __restrict__ skipw,
    float* __restrict__ hstate) {
  const int gw = (blockIdx.x * 256 + threadIdx.x) >> 6;   // (b*S+s)*4 + n
  const int lane = threadIdx.x & 63;
  const int n = gw & 3;
  const int p = gw >> 2;
  const int b = p >> 10, s = p & 1023;
  const float* hp = hb + (((size_t)b * NHM_ + n) * S_ + s) * DHM_;
  const float x1 = hp[lane];
  const float x2 = (lane < 8) ? hp[64 + lane] : 0.f;
  float sum = x1 + x2;
#pragma unroll
  for (int off = 32; off >= 1; off >>= 1) sum += __shfl_xor(sum, off);
  const float mean = sum * (1.f / 72.f);
  const float d1 = x1 - mean;
  const float d2 = (lane < 8) ? (x2 - mean) : 0.f;
  float ss = d1 * d1 + d2 * d2;
#pragma unroll
  for (int off = 32; off >= 1; off >>= 1) ss += __shfl_xor(ss, off);
  const float inv = rsqrtf(ss * (1.f / 72.f) + 1e-5f);
  {
    const int c = n * DHM_ + lane;
    const float hn = d1 * inv * normw[c];
    const float xav = xa[(size_t)p * INNER_ + c];
    const float z = y[(size_t)p * 576 + 288 + c];
    const float sz = z / (1.f + expf(-z));
    hstate[(size_t)p * INNER_ + c] = (hn + skipw[c] * xav) * sz;
  }
  if (lane < 8) {
    const int c = n * DHM_ + 64 + lane;
    const float hn = d2 * inv * normw[c];
    const float xav = xa[(size_t)p * INNER_ + c];
    const float z = y[(size_t)p * 576 + 288 + c];
    const float sz = z / (1.f + expf(-z));
    hstate[(size_t)p * INNER_ + c] = (hn + skipw[c] * xav) * sz;
  }
}

extern "C" void kernel_launch(void* const* d_in, const int* in_sizes, int n_in,
                              void* d_out, int out_size, void* d_ws, size_t ws_size,
                              hipStream_t stream) {
  const float* x           = (const float*)d_in[0];
  const float* proj_up_w   = (const float*)d_in[1];
  const float* q_w         = (const float*)d_in[2];
  const float* k_w         = (const float*)d_in[3];
  const float* v_w         = (const float*)d_in[4];
  const float* conv_w      = (const float*)d_in[5];
  const float* ig_w        = (const float*)d_in[6];
  const float* ig_b        = (const float*)d_in[7];
  const float* fg_w        = (const float*)d_in[8];
  const float* fg_b        = (const float*)d_in[9];
  const float* norm_w      = (const float*)d_in[10];
  const float* skipw       = (const float*)d_in[11];
  const float* proj_down_w = (const float*)d_in[12];
  float* out = (float*)d_out;

  float* ws = (float*)d_ws;
  float* y      = ws;                        // 8192*576
  float* xa     = y      + (size_t)8192 * 576;
  float* qh     = xa     + (size_t)8192 * 288;
  float* kh     = qh     + (size_t)8192 * 288;
  float* vh     = kh     + (size_t)8192 * 288;
  float* igb_   = vh     + (size_t)8192 * 288;   // B*4*S
  float* fgb_   = igb_   + 32768;
  float* lfcb   = fgb_   + 32768;
  float* gbuf   = lfcb   + 32768;
  float* Mbuf   = gbuf   + 32768;
  float* hb     = Mbuf   + 32768;                // B*4*S*72
  float* hstate = hb     + (size_t)8192 * 288;

  // 1. proj_up: y = x @ proj_up_w^T   (8192x576, K=192)
  gemm_bt<<<dim3(576 / 64, 8192 / 64), 256, 0, stream>>>(x, proj_up_w, y, 8192, 576, 192);
  // 2. depthwise conv + silu -> xa
  conv_silu_kernel<<<(8192 * 288) / 256, 256, 0, stream>>>(y, conv_w, xa);
  // 3. headwise q/k/v -> head layout
  headwise_kernel<<<(8192 * 288) / 256, 256, 0, stream>>>(y, xa, q_w, k_w, v_w, qh, kh, vh);
  // 4. gates
  gates_kernel<<<8192 / 4, 256, 0, stream>>>(qh, kh, vh, ig_w, ig_b, fg_w, fg_b, igb_, fgb_);
  // 5. per-(b,n) scans
  scan_kernel<<<B_ * NHM_, 256, 0, stream>>>(fgb_, igb_, lfcb, gbuf, Mbuf);
  // 6. mLSTM core
  mlstm_kernel<<<B_ * NHM_ * (S_ / 64), 256, 0, stream>>>(qh, kh, vh, gbuf, Mbuf, lfcb, hb);
  // 7. LN + skip + silu(z)
  ln_fuse_kernel<<<(8192 * 4) / 4, 256, 0, stream>>>(hb, xa, y, norm_w, skipw, hstate);
  // 8. proj_down -> out
  gemm_bt<<<dim3(192 / 64, 8192 / 64), 256, 0, stream>>>(hstate, proj_down_w, out, 8192, 192, 288);
}

// Round 2
// 234.410 us; speedup vs baseline: 2.6747x; 2.6747x over previous
//
#include <hip/hip_runtime.h>
#include <math.h>

#define B_ 8
#define S_ 1024
#define INNER_ 288
#define NHM_ 4
#define DHM_ 72
#define H_ 32
#define W_ 32

typedef unsigned short ushort_t;
typedef unsigned int uint_t;
typedef __bf16 bf16x8 __attribute__((ext_vector_type(8)));
typedef float f32x4 __attribute__((ext_vector_type(4)));

__device__ __forceinline__ ushort_t f2bf(float f) {
  union { float f; unsigned u; } v; v.f = f;
  unsigned r = v.u + 0x7FFF + ((v.u >> 16) & 1);
  return (ushort_t)(r >> 16);
}
__device__ __forceinline__ float bf2f(ushort_t u) {
  union { unsigned u; float f; } v; v.u = ((unsigned)u) << 16;
  return v.f;
}
__device__ __forceinline__ void gl16(const void* g, void* l) {
  __builtin_amdgcn_global_load_lds(
      (const __attribute__((address_space(1))) void*)g,
      (__attribute__((address_space(3))) void*)l, 16, 0, 0);
}

// ---------------- GEMM: C[M,N] = A[M,K] * B[N,K]^T (fp32) ------------------
__global__ __launch_bounds__(256) void gemm_bt(
    const float* __restrict__ A, const float* __restrict__ Bm,
    float* __restrict__ C, int M, int N, int K) {
  __shared__ float As[16][68];
  __shared__ float Bs[16][68];
  const int m0 = blockIdx.y * 64, n0 = blockIdx.x * 64;
  const int tid = threadIdx.x;
  const int tx = tid & 15, ty = tid >> 4;
  const int lr = tid >> 2;
  const int lk = (tid & 3) << 2;
  float acc[4][4] = {};
  for (int k0 = 0; k0 < K; k0 += 16) {
    const float4 av = *reinterpret_cast<const float4*>(&A[(size_t)(m0 + lr) * K + k0 + lk]);
    const float4 bv = *reinterpret_cast<const float4*>(&Bm[(size_t)(n0 + lr) * K + k0 + lk]);
    __syncthreads();
    As[lk + 0][lr] = av.x; As[lk + 1][lr] = av.y; As[lk + 2][lr] = av.z; As[lk + 3][lr] = av.w;
    Bs[lk + 0][lr] = bv.x; Bs[lk + 1][lr] = bv.y; Bs[lk + 2][lr] = bv.z; Bs[lk + 3][lr] = bv.w;
    __syncthreads();
#pragma unroll
    for (int kk = 0; kk < 16; ++kk) {
      const float4 a4 = *reinterpret_cast<const float4*>(&As[kk][ty * 4]);
      const float4 b4 = *reinterpret_cast<const float4*>(&Bs[kk][tx * 4]);
      const float a[4] = {a4.x, a4.y, a4.z, a4.w};
      const float b[4] = {b4.x, b4.y, b4.z, b4.w};
#pragma unroll
      for (int i = 0; i < 4; ++i)
#pragma unroll
        for (int j = 0; j < 4; ++j) acc[i][j] += a[i] * b[j];
    }
  }
#pragma unroll
  for (int i = 0; i < 4; ++i) {
    const size_t m = (size_t)m0 + ty * 4 + i;
    float4 o; o.x = acc[i][0]; o.y = acc[i][1]; o.z = acc[i][2]; o.w = acc[i][3];
    *reinterpret_cast<float4*>(&C[m * N + n0 + tx * 4]) = o;
  }
}

// ---------------- depthwise 3x3 conv (SAME) + SiLU -------------------------
__global__ __launch_bounds__(256) void conv_silu_kernel(
    const float* __restrict__ y, const float* __restrict__ cw, float* __restrict__ xa) {
  const int idx = blockIdx.x * 256 + threadIdx.x;
  const int c = idx % INNER_;
  const int p = idx / INNER_;
  const int xx = p & 31, yy = (p >> 5) & 31, b = p >> 10;
  float acc = 0.f;
#pragma unroll
  for (int ky = 0; ky < 3; ++ky) {
    const int iy = yy + ky - 1;
    if (iy < 0 || iy >= H_) continue;
#pragma unroll
    for (int kx = 0; kx < 3; ++kx) {
      const int ix = xx + kx - 1;
      if (ix < 0 || ix >= W_) continue;
      acc += y[((size_t)((b << 10) + (iy << 5) + ix)) * 576 + c] * cw[(ky * 3 + kx) * INNER_ + c];
    }
  }
  xa[(size_t)p * INNER_ + c] = acc / (1.f + expf(-acc));
}

// ---------------- headwise q/k/v -> bf16 (q,k padded to pitch 96) ----------
__global__ __launch_bounds__(256) void headwise_kernel(
    const float* __restrict__ y, const float* __restrict__ xa,
    const float* __restrict__ qw, const float* __restrict__ kw, const float* __restrict__ vw,
    ushort_t* __restrict__ qg, ushort_t* __restrict__ kg, ushort_t* __restrict__ vg) {
  const int idx = blockIdx.x * 256 + threadIdx.x;   // over 32*1024*96
  const int d96 = idx % 96;
  const int r = idx / 96;             // bn*1024 + s
  if (d96 >= 72) { qg[idx] = 0; kg[idx] = 0; return; }
  const int s = r & 1023;
  const int bn = r >> 10;
  const int b = bn >> 2, n = bn & 3;
  const int c = n * DHM_ + d96;
  const int hq = c >> 2, o = c & 3;
  const int p = (b << 10) + s;
  const float* xav = &xa[(size_t)p * INNER_ + (hq << 2)];
  const float* xmv = &y[(size_t)p * 576 + (hq << 2)];
  float q = 0.f, k = 0.f, v = 0.f;
#pragma unroll
  for (int d = 0; d < 4; ++d) {
    const int wi = hq * 16 + o * 4 + d;
    q += qw[wi] * xav[d];
    k += kw[wi] * xav[d];
    v += vw[wi] * xmv[d];
  }
  qg[idx] = f2bf(q); kg[idx] = f2bf(k);
  vg[(size_t)r * DHM_ + d96] = f2bf(v);
}

// ---------------- V transpose: vg[bn][s][72] -> vtg[bn][72][1024] ----------
__global__ __launch_bounds__(256) void vtrans_kernel(
    const ushort_t* __restrict__ vg, ushort_t* __restrict__ vtg) {
  __shared__ ushort_t T[64][82];
  const int bn = blockIdx.x >> 4;
  const int s0 = (blockIdx.x & 15) << 6;
  const int tid = threadIdx.x;
  const uint_t* v32 = (const uint_t*)vg;
  for (int i = tid; i < 2304; i += 256) {
    const int r = i / 36, c2 = i % 36;
    const uint_t val = v32[((size_t)(bn * 1024 + s0 + r)) * 36 + c2];
    *(uint_t*)&T[r][c2 * 2] = val;
  }
  __syncthreads();
  uint_t* o32 = (uint_t*)vtg;
  for (int i = tid; i < 2304; i += 256) {
    const int d = i >> 5, m = i & 31;
    const uint_t val = (uint_t)T[2 * m][d] | ((uint_t)T[2 * m + 1][d] << 16);
    o32[((size_t)bn * 72 + d) * 512 + (s0 >> 1) + m] = val;
  }
}

// ---------------- gates (bf16 inputs) --------------------------------------
__global__ __launch_bounds__(256) void gates_kernel(
    const ushort_t* __restrict__ qg, const ushort_t* __restrict__ kg, const ushort_t* __restrict__ vg,
    const float* __restrict__ igw, const float* __restrict__ igb,
    const float* __restrict__ fgw, const float* __restrict__ fgb,
    float* __restrict__ ig, float* __restrict__ fg) {
  const int gw = (blockIdx.x * 256 + threadIdx.x) >> 6;  // b*S+s
  const int lane = threadIdx.x & 63;
  const int b = gw >> 10, s = gw & 1023;
  float iacc[4] = {}, facc[4] = {};
  for (int j = lane; j < 864; j += 64) {
    const int part = j / INNER_;
    const int c = j - part * INNER_;
    const int n = c / DHM_, d = c % DHM_;
    ushort_t u;
    if (part == 0)      u = qg[((size_t)(b * 4 + n) * 1024 + s) * 96 + d];
    else if (part == 1) u = kg[((size_t)(b * 4 + n) * 1024 + s) * 96 + d];
    else                u = vg[((size_t)(b * 4 + n) * 1024 + s) * 72 + d];
    const float gv = bf2f(u);
#pragma unroll
    for (int nn = 0; nn < 4; ++nn) {
      iacc[nn] += gv * igw[nn * 864 + j];
      facc[nn] += gv * fgw[nn * 864 + j];
    }
  }
#pragma unroll
  for (int off = 32; off >= 1; off >>= 1) {
#pragma unroll
    for (int nn = 0; nn < 4; ++nn) {
      iacc[nn] += __shfl_xor(iacc[nn], off);
      facc[nn] += __shfl_xor(facc[nn], off);
    }
  }
  if (lane == 0) {
#pragma unroll
    for (int nn = 0; nn < 4; ++nn) {
      ig[((size_t)b * NHM_ + nn) * S_ + s] = iacc[nn] + igb[nn];
      fg[((size_t)b * NHM_ + nn) * S_ + s] = facc[nn] + fgb[nn];
    }
  }
}

// ---------------- per-(b,n) scans ------------------------------------------
__global__ __launch_bounds__(256) void scan_kernel(
    const float* __restrict__ fg, const float* __restrict__ ig,
    float* __restrict__ lfc, float* __restrict__ g, float* __restrict__ Mb) {
  __shared__ float sd[256];
  const int bn = blockIdx.x;
  const int tid = threadIdx.x;
  const float* fgp = &fg[(size_t)bn * S_];
  const float* igp = &ig[(size_t)bn * S_];
  float lf[4];
#pragma unroll
  for (int i = 0; i < 4; ++i) {
    const float f = fgp[tid * 4 + i];
    lf[i] = (f >= 0.f) ? -log1pf(expf(-f)) : (f - log1pf(expf(f)));
  }
  float p[4];
  p[0] = lf[0]; p[1] = p[0] + lf[1]; p[2] = p[1] + lf[2]; p[3] = p[2] + lf[3];
  sd[tid] = p[3];
  __syncthreads();
  for (int off = 1; off < 256; off <<= 1) {
    const float v = (tid >= off) ? sd[tid - off] : 0.f;
    __syncthreads();
    sd[tid] += v;
    __syncthreads();
  }
  const float excl = sd[tid] - p[3];
  float l[4];
#pragma unroll
  for (int i = 0; i < 4; ++i) {
    l[i] = excl + p[i];
    lfc[(size_t)bn * S_ + tid * 4 + i] = l[i];
  }
  float gv[4], pm[4];
#pragma unroll
  for (int i = 0; i < 4; ++i) gv[i] = igp[tid * 4 + i] - l[i];
  pm[0] = gv[0];
#pragma unroll
  for (int i = 1; i < 4; ++i) pm[i] = fmaxf(pm[i - 1], gv[i]);
  __syncthreads();
  sd[tid] = pm[3];
  __syncthreads();
  for (int off = 1; off < 256; off <<= 1) {
    const float v = (tid >= off) ? sd[tid - off] : -INFINITY;
    __syncthreads();
    sd[tid] = fmaxf(sd[tid], v);
    __syncthreads();
  }
  const float exclm = (tid > 0) ? sd[tid - 1] : -INFINITY;
#pragma unroll
  for (int i = 0; i < 4; ++i) {
    g[(size_t)bn * S_ + tid * 4 + i] = gv[i];
    Mb[(size_t)bn * S_ + tid * 4 + i] = fmaxf(exclm, pm[i]);
  }
}

// ---------------- mLSTM core: bf16 MFMA flash-style ------------------------
__global__ __launch_bounds__(256) void mlstm_mfma(
    const ushort_t* __restrict__ qg, const ushort_t* __restrict__ kg,
    const ushort_t* __restrict__ vtg,
    const float* __restrict__ gb, const float* __restrict__ Mb, const float* __restrict__ lfc,
    float* __restrict__ hb) {
  __shared__ __align__(16) ushort_t Qs[64 * 96];
  __shared__ __align__(16) ushort_t Ks[64 * 96];
  __shared__ __align__(16) ushort_t Vt[80 * 64];   // [d][t], XOR-16B swizzled rows
  __shared__ __align__(16) ushort_t Ps[64 * 72];
  __shared__ float Ms_s[64], en_s[64];
  // balanced pairing: co-resident block pair does st + (15-st) tiles
  const int xb = blockIdx.x;
  const int pp = xb >> 1, odd = xb & 1;
  const int bn = pp >> 3, jj0 = pp & 7;
  const int st = odd ? (15 - jj0) : jj0;
  const int s0 = st << 6;
  const int tid = threadIdx.x, lane = tid & 63, wv = tid >> 6;
  const int cl = lane & 15, rowb = lane >> 4;
  const ushort_t* qb = qg + (size_t)bn * 1024 * 96;
  const ushort_t* kb = kg + (size_t)bn * 1024 * 96;
  const char* vtb = (const char*)(vtg + (size_t)bn * 72 * 1024);
  // stage Q tile (linear: padded global pitch == LDS pitch = 192B)
  for (int i = wv; i < 12; i += 4)
    gl16(qb + (size_t)s0 * 96 + i * 512 + lane * 8, Qs + i * 512);
  if (tid < 64) {
    const float m = Mb[bn * S_ + s0 + tid];
    Ms_s[tid] = m;
    en_s[tid] = __expf(-(lfc[bn * S_ + s0 + tid] + m));
  }
  // ones-column (d=72) + zero pad rows 73..79 of Vt (never restaged)
  Vt[72 * 64 + tid] = (tid < 64) ? (ushort_t)0x3F80 : (ushort_t)0;
  Vt[72 * 64 + 256 + tid] = 0;
  f32x4 accv[5];
#pragma unroll
  for (int n0 = 0; n0 < 5; ++n0) accv[n0] = (f32x4){0.f, 0.f, 0.f, 0.f};
  const float rsc = 0.11785113019775793f;   // 1/sqrt(72)

  for (int tt = 0; tt <= st; ++tt) {
    const int t0 = tt << 6;
    __syncthreads();                      // prev-iter consumers done
    // stage K (12 instr) + Vt (9 instr, inverse-swizzled global source)
    for (int i = wv; i < 21; i += 4) {
      if (i < 12) {
        gl16(kb + (size_t)t0 * 96 + i * 512 + lane * 8, Ks + i * 512);
      } else {
        const int j = i - 12;
        const int o = j * 1024 + lane * 16;       // dest byte (linear)
        const int d = o >> 7;
        const int c = o & 127;
        const int ct = c ^ ((d & 7) << 4);
        gl16(vtb + (size_t)d * 2048 + t0 * 2 + ct, (char*)Vt + j * 1024);
      }
    }
    __syncthreads();                      // staging visible (vmcnt drained)
    // ---- QK^T: 4 tiles of 16x16, K=96 (cols 72..95 are zero) ----
    f32x4 qk[4];
#pragma unroll
    for (int n0 = 0; n0 < 4; ++n0) qk[n0] = (f32x4){0.f, 0.f, 0.f, 0.f};
#pragma unroll
    for (int k0 = 0; k0 < 96; k0 += 32) {
      const bf16x8 a = *(const bf16x8*)&Qs[(16 * wv + cl) * 96 + k0 + rowb * 8];
#pragma unroll
      for (int n0 = 0; n0 < 4; ++n0) {
        const bf16x8 b = *(const bf16x8*)&Ks[(n0 * 16 + cl) * 96 + k0 + rowb * 8];
        qk[n0] = __builtin_amdgcn_mfma_f32_16x16x32_bf16(a, b, qk[n0], 0, 0, 0);
      }
    }
    // ---- decay weight + causal mask -> Ps (bf16) ----
#pragma unroll
    for (int n0 = 0; n0 < 4; ++n0) {
      const int tc = t0 + n0 * 16 + cl;
      const float gtv = gb[bn * S_ + tc];
#pragma unroll
      for (int i = 0; i < 4; ++i) {
        const int srl = 16 * wv + 4 * rowb + i;
        const int sr = s0 + srl;
        const float w = (tc <= sr) ? qk[n0][i] * rsc * __expf(gtv - Ms_s[srl]) : 0.f;
        Ps[srl * 72 + n0 * 16 + cl] = f2bf(w);
      }
    }
    // ---- PV: 5 tiles of 16x16 over d (incl. ones-col), K=64 ----
#pragma unroll
    for (int k0 = 0; k0 < 64; k0 += 32) {
      const bf16x8 a = *(const bf16x8*)&Ps[(16 * wv + cl) * 72 + k0 + rowb * 8];
#pragma unroll
      for (int n0 = 0; n0 < 5; ++n0) {
        const int d = n0 * 16 + cl;
        const int ct0 = (k0 + rowb * 8) * 2;
        const int addr = d * 128 + (ct0 ^ ((d & 7) << 4));
        const bf16x8 b = *(const bf16x8*)((const char*)Vt + addr);
        accv[n0] = __builtin_amdgcn_mfma_f32_16x16x32_bf16(a, b, accv[n0], 0, 0, 0);
      }
    }
  }
  // ---- epilogue: rowsum col (d=72) -> normalizer -> store ----
  float inv[4];
#pragma unroll
  for (int i = 0; i < 4; ++i) {
    const float rs = __shfl(accv[4][i], (lane & 48) + 8, 64);
    const int srl = 16 * wv + 4 * rowb + i;
    inv[i] = 1.f / (fmaxf(fabsf(rs), en_s[srl]) + 1e-6f);
  }
  float* hp = hb + ((size_t)bn * S_ + s0) * DHM_;
#pragma unroll
  for (int n0 = 0; n0 < 5; ++n0) {
    const int d = n0 * 16 + cl;
    if (d < 72) {
#pragma unroll
      for (int i = 0; i < 4; ++i) {
        const int srl = 16 * wv + 4 * rowb + i;
        hp[(size_t)srl * DHM_ + d] = accv[n0][i] * inv[i];
      }
    }
  }
}

// ---------------- headwise LN + skip + silu(z) gate ------------------------
__global__ __launch_bounds__(256) void ln_fuse_kernel(
    const float* __restrict__ hb, const float* __restrict__ xa, const float* __restrict__ y,
    const float* __restrict__ normw, const float* __restrict__ skipw,
    float* __restrict__ hstate) {
  const int gw = (blockIdx.x * 256 + threadIdx.x) >> 6;   // (b*S+s)*4 + n
  const int lane = threadIdx.x & 63;
  const int n = gw & 3;
  const int p = gw >> 2;
  const int b = p >> 10, s = p & 1023;
  const float* hp = hb + (((size_t)b * NHM_ + n) * S_ + s) * DHM_;
  const float x1 = hp[lane];
  const float x2 = (lane < 8) ? hp[64 + lane] : 0.f;
  float sum = x1 + x2;
#pragma unroll
  for (int off = 32; off >= 1; off >>= 1) sum += __shfl_xor(sum, off);
  const float mean = sum * (1.f / 72.f);
  const float d1 = x1 - mean;
  const float d2 = (lane < 8) ? (x2 - mean) : 0.f;
  float ss = d1 * d1 + d2 * d2;
#pragma unroll
  for (int off = 32; off >= 1; off >>= 1) ss += __shfl_xor(ss, off);
  const float inv = rsqrtf(ss * (1.f / 72.f) + 1e-5f);
  {
    const int c = n * DHM_ + lane;
    const float hn = d1 * inv * normw[c];
    const float xav = xa[(size_t)p * INNER_ + c];
    const float z = y[(size_t)p * 576 + 288 + c];
    const float sz = z / (1.f + expf(-z));
    hstate[(size_t)p * INNER_ + c] = (hn + skipw[c] * xav) * sz;
  }
  if (lane < 8) {
    const int c = n * DHM_ + 64 + lane;
    const float hn = d2 * inv * normw[c];
    const float xav = xa[(size_t)p * INNER_ + c];
    const float z = y[(size_t)p * 576 + 288 + c];
    const float sz = z / (1.f + expf(-z));
    hstate[(size_t)p * INNER_ + c] = (hn + skipw[c] * xav) * sz;
  }
}

extern "C" void kernel_launch(void* const* d_in, const int* in_sizes, int n_in,
                              void* d_out, int out_size, void* d_ws, size_t ws_size,
                              hipStream_t stream) {
  const float* x           = (const float*)d_in[0];
  const float* proj_up_w   = (const float*)d_in[1];
  const float* q_w         = (const float*)d_in[2];
  const float* k_w         = (const float*)d_in[3];
  const float* v_w         = (const float*)d_in[4];
  const float* conv_w      = (const float*)d_in[5];
  const float* ig_w        = (const float*)d_in[6];
  const float* ig_b        = (const float*)d_in[7];
  const float* fg_w        = (const float*)d_in[8];
  const float* fg_b        = (const float*)d_in[9];
  const float* norm_w      = (const float*)d_in[10];
  const float* skipw       = (const float*)d_in[11];
  const float* proj_down_w = (const float*)d_in[12];
  float* out = (float*)d_out;

  float* ws = (float*)d_ws;
  float* y      = ws;                            // 8192*576
  float* xa     = y      + (size_t)8192 * 576;   // 8192*288
  float* igb_   = xa     + (size_t)8192 * 288;   // 32768
  float* fgb_   = igb_   + 32768;
  float* lfcb   = fgb_   + 32768;
  float* gbuf   = lfcb   + 32768;
  float* Mbuf   = gbuf   + 32768;
  float* hbuf   = Mbuf   + 32768;                // 8192*288
  float* hstate = hbuf   + (size_t)8192 * 288;   // 8192*288
  ushort_t* qg  = (ushort_t*)(hstate + (size_t)8192 * 288);  // 32*1024*96
  ushort_t* kg  = qg + (size_t)32 * 1024 * 96;
  ushort_t* vg  = kg + (size_t)32 * 1024 * 96;               // 32*1024*72
  ushort_t* vtg = vg + (size_t)32 * 1024 * 72;               // 32*72*1024

  // 1. proj_up
  gemm_bt<<<dim3(576 / 64, 8192 / 64), 256, 0, stream>>>(x, proj_up_w, y, 8192, 576, 192);
  // 2. conv + silu
  conv_silu_kernel<<<(8192 * 288) / 256, 256, 0, stream>>>(y, conv_w, xa);
  // 3. headwise -> bf16 q/k (pitch 96) + v
  headwise_kernel<<<(32 * 1024 * 96) / 256, 256, 0, stream>>>(y, xa, q_w, k_w, v_w, qg, kg, vg);
  // 4. V transpose -> [bn][72][1024]
  vtrans_kernel<<<512, 256, 0, stream>>>(vg, vtg);
  // 5. gates
  gates_kernel<<<8192 / 4, 256, 0, stream>>>(qg, kg, vg, ig_w, ig_b, fg_w, fg_b, igb_, fgb_);
  // 6. scans
  scan_kernel<<<B_ * NHM_, 256, 0, stream>>>(fgb_, igb_, lfcb, gbuf, Mbuf);
  // 7. mLSTM core (bf16 MFMA)
  mlstm_mfma<<<512, 256, 0, stream>>>(qg, kg, vtg, gbuf, Mbuf, lfcb, hbuf);
  // 8. LN + skip + silu(z)
  ln_fuse_kernel<<<(8192 * 4) / 4, 256, 0, stream>>>(hbuf, xa, y, norm_w, skipw, hstate);
  // 9. proj_down
  gemm_bt<<<dim3(192 / 64, 8192 / 64), 256, 0, stream>>>(hstate, proj_down_w, out, 8192, 192, 288);
}

// Round 3
// 212.147 us; speedup vs baseline: 2.9554x; 1.1049x over previous
//
#include <hip/hip_runtime.h>
#include <math.h>

#define B_ 8
#define S_ 1024
#define INNER_ 288
#define NHM_ 4
#define DHM_ 72
#define H_ 32
#define W_ 32

typedef unsigned short ushort_t;
typedef unsigned int uint_t;
typedef __bf16 bf16x8 __attribute__((ext_vector_type(8)));
typedef float f32x4 __attribute__((ext_vector_type(4)));

__device__ __forceinline__ ushort_t f2bf(float f) {
  union { float f; unsigned u; } v; v.f = f;
  unsigned r = v.u + 0x7FFF + ((v.u >> 16) & 1);
  return (ushort_t)(r >> 16);
}
__device__ __forceinline__ float bf2f(ushort_t u) {
  union { unsigned u; float f; } v; v.u = ((unsigned)u) << 16;
  return v.f;
}
__device__ __forceinline__ void gl16(const void* g, void* l) {
  __builtin_amdgcn_global_load_lds(
      (const __attribute__((address_space(1))) void*)g,
      (__attribute__((address_space(3))) void*)l, 16, 0, 0);
}

// ---------------- bf16 MFMA GEMM: C[M,N] = A[M,K] @ B[N,K]^T ----------------
// A,B are fp32 in global; converted to bf16 during reg-staging. C fp32.
// 4 waves in 2x2; wave tile (BM/2)x(BN/2); frags 16x16, K-step 32.
template<int BM, int BN, int BK, int NSTEP>
__global__ __launch_bounds__(256) void gemm_mfma_bt(
    const float* __restrict__ A, const float* __restrict__ Bm,
    float* __restrict__ C, int M, int N, int K) {
  constexpr int PITCH = BK + 8;
  constexpr int FM = BM / 32, FN = BN / 32;
  __shared__ __align__(16) ushort_t As[BM * PITCH];
  __shared__ __align__(16) ushort_t Bs[BN * PITCH];
  const int tid = threadIdx.x, lane = tid & 63, wv = tid >> 6;
  const int wm = wv >> 1, wn = wv & 1;
  const int cl = lane & 15, rowb = lane >> 4;
  const int m0 = blockIdx.y * BM, n0 = blockIdx.x * BN;
  f32x4 acc[FM][FN];
#pragma unroll
  for (int mi = 0; mi < FM; ++mi)
#pragma unroll
    for (int nj = 0; nj < FN; ++nj) acc[mi][nj] = (f32x4){0.f, 0.f, 0.f, 0.f};

  for (int s = 0; s < NSTEP; ++s) {
    const int k0g = s * BK;
    if (s > 0) __syncthreads();
    constexpr int NA4 = BM * BK / 4 / 256;
#pragma unroll
    for (int i = 0; i < NA4; ++i) {
      const int f4 = i * 256 + tid;
      const int r = (f4 * 4) / BK, c = (f4 * 4) % BK;
      const float4 v = *reinterpret_cast<const float4*>(&A[(size_t)(m0 + r) * K + k0g + c]);
      ushort4 w;
      w.x = f2bf(v.x); w.y = f2bf(v.y); w.z = f2bf(v.z); w.w = f2bf(v.w);
      *reinterpret_cast<ushort4*>(&As[r * PITCH + c]) = w;
    }
    constexpr int NB4 = BN * BK / 4 / 256;
#pragma unroll
    for (int i = 0; i < NB4; ++i) {
      const int f4 = i * 256 + tid;
      const int r = (f4 * 4) / BK, c = (f4 * 4) % BK;
      const float4 v = *reinterpret_cast<const float4*>(&Bm[(size_t)(n0 + r) * K + k0g + c]);
      ushort4 w;
      w.x = f2bf(v.x); w.y = f2bf(v.y); w.z = f2bf(v.z); w.w = f2bf(v.w);
      *reinterpret_cast<ushort4*>(&Bs[r * PITCH + c]) = w;
    }
    __syncthreads();
#pragma unroll
    for (int kk = 0; kk < BK; kk += 32) {
      bf16x8 af[FM], bfr[FN];
#pragma unroll
      for (int mi = 0; mi < FM; ++mi)
        af[mi] = *reinterpret_cast<const bf16x8*>(
            &As[(wm * (BM / 2) + mi * 16 + cl) * PITCH + kk + rowb * 8]);
#pragma unroll
      for (int nj = 0; nj < FN; ++nj)
        bfr[nj] = *reinterpret_cast<const bf16x8*>(
            &Bs[(wn * (BN / 2) + nj * 16 + cl) * PITCH + kk + rowb * 8]);
#pragma unroll
      for (int mi = 0; mi < FM; ++mi)
#pragma unroll
        for (int nj = 0; nj < FN; ++nj)
          acc[mi][nj] = __builtin_amdgcn_mfma_f32_16x16x32_bf16(af[mi], bfr[nj], acc[mi][nj], 0, 0, 0);
    }
  }
#pragma unroll
  for (int mi = 0; mi < FM; ++mi)
#pragma unroll
    for (int i = 0; i < 4; ++i) {
      const size_t m = m0 + wm * (BM / 2) + mi * 16 + rowb * 4 + i;
#pragma unroll
      for (int nj = 0; nj < FN; ++nj) {
        const int n = n0 + wn * (BN / 2) + nj * 16 + cl;
        C[m * N + n] = acc[mi][nj][i];
      }
    }
}

// ---------------- depthwise 3x3 conv (SAME) + SiLU -------------------------
__global__ __launch_bounds__(256) void conv_silu_kernel(
    const float* __restrict__ y, const float* __restrict__ cw, float* __restrict__ xa) {
  const int idx = blockIdx.x * 256 + threadIdx.x;
  const int c = idx % INNER_;
  const int p = idx / INNER_;
  const int xx = p & 31, yy = (p >> 5) & 31, b = p >> 10;
  float acc = 0.f;
#pragma unroll
  for (int ky = 0; ky < 3; ++ky) {
    const int iy = yy + ky - 1;
    if (iy < 0 || iy >= H_) continue;
#pragma unroll
    for (int kx = 0; kx < 3; ++kx) {
      const int ix = xx + kx - 1;
      if (ix < 0 || ix >= W_) continue;
      acc += y[((size_t)((b << 10) + (iy << 5) + ix)) * 576 + c] * cw[(ky * 3 + kx) * INNER_ + c];
    }
  }
  xa[(size_t)p * INNER_ + c] = acc / (1.f + expf(-acc));
}

// ---------------- headwise q/k/v -> bf16 (q,k padded to pitch 96) ----------
__global__ __launch_bounds__(256) void headwise_kernel(
    const float* __restrict__ y, const float* __restrict__ xa,
    const float* __restrict__ qw, const float* __restrict__ kw, const float* __restrict__ vw,
    ushort_t* __restrict__ qg, ushort_t* __restrict__ kg, ushort_t* __restrict__ vg) {
  const int idx = blockIdx.x * 256 + threadIdx.x;   // over 32*1024*96
  const int d96 = idx % 96;
  const int r = idx / 96;             // bn*1024 + s
  if (d96 >= 72) { qg[idx] = 0; kg[idx] = 0; return; }
  const int s = r & 1023;
  const int bn = r >> 10;
  const int b = bn >> 2, n = bn & 3;
  const int c = n * DHM_ + d96;
  const int hq = c >> 2, o = c & 3;
  const int p = (b << 10) + s;
  const float* xav = &xa[(size_t)p * INNER_ + (hq << 2)];
  const float* xmv = &y[(size_t)p * 576 + (hq << 2)];
  float q = 0.f, k = 0.f, v = 0.f;
#pragma unroll
  for (int d = 0; d < 4; ++d) {
    const int wi = hq * 16 + o * 4 + d;
    q += qw[wi] * xav[d];
    k += kw[wi] * xav[d];
    v += vw[wi] * xmv[d];
  }
  qg[idx] = f2bf(q); kg[idx] = f2bf(k);
  vg[(size_t)r * DHM_ + d96] = f2bf(v);
}

// ---------------- V transpose: vg[bn][s][72] -> vtg[bn][72][1024] ----------
__global__ __launch_bounds__(256) void vtrans_kernel(
    const ushort_t* __restrict__ vg, ushort_t* __restrict__ vtg) {
  __shared__ ushort_t T[64][82];
  const int bn = blockIdx.x >> 4;
  const int s0 = (blockIdx.x & 15) << 6;
  const int tid = threadIdx.x;
  const uint_t* v32 = (const uint_t*)vg;
  for (int i = tid; i < 2304; i += 256) {
    const int r = i / 36, c2 = i % 36;
    const uint_t val = v32[((size_t)(bn * 1024 + s0 + r)) * 36 + c2];
    *(uint_t*)&T[r][c2 * 2] = val;
  }
  __syncthreads();
  uint_t* o32 = (uint_t*)vtg;
  for (int i = tid; i < 2304; i += 256) {
    const int d = i >> 5, m = i & 31;
    const uint_t val = (uint_t)T[2 * m][d] | ((uint_t)T[2 * m + 1][d] << 16);
    o32[((size_t)bn * 72 + d) * 512 + (s0 >> 1) + m] = val;
  }
}

// ---------------- gates (bf16 inputs) --------------------------------------
__global__ __launch_bounds__(256) void gates_kernel(
    const ushort_t* __restrict__ qg, const ushort_t* __restrict__ kg, const ushort_t* __restrict__ vg,
    const float* __restrict__ igw, const float* __restrict__ igb,
    const float* __restrict__ fgw, const float* __restrict__ fgb,
    float* __restrict__ ig, float* __restrict__ fg) {
  const int gw = (blockIdx.x * 256 + threadIdx.x) >> 6;  // b*S+s
  const int lane = threadIdx.x & 63;
  const int b = gw >> 10, s = gw & 1023;
  float iacc[4] = {}, facc[4] = {};
  for (int j = lane; j < 864; j += 64) {
    const int part = j / INNER_;
    const int c = j - part * INNER_;
    const int n = c / DHM_, d = c % DHM_;
    ushort_t u;
    if (part == 0)      u = qg[((size_t)(b * 4 + n) * 1024 + s) * 96 + d];
    else if (part == 1) u = kg[((size_t)(b * 4 + n) * 1024 + s) * 96 + d];
    else                u = vg[((size_t)(b * 4 + n) * 1024 + s) * 72 + d];
    const float gv = bf2f(u);
#pragma unroll
    for (int nn = 0; nn < 4; ++nn) {
      iacc[nn] += gv * igw[nn * 864 + j];
      facc[nn] += gv * fgw[nn * 864 + j];
    }
  }
#pragma unroll
  for (int off = 32; off >= 1; off >>= 1) {
#pragma unroll
    for (int nn = 0; nn < 4; ++nn) {
      iacc[nn] += __shfl_xor(iacc[nn], off);
      facc[nn] += __shfl_xor(facc[nn], off);
    }
  }
  if (lane == 0) {
#pragma unroll
    for (int nn = 0; nn < 4; ++nn) {
      ig[((size_t)b * NHM_ + nn) * S_ + s] = iacc[nn] + igb[nn];
      fg[((size_t)b * NHM_ + nn) * S_ + s] = facc[nn] + fgb[nn];
    }
  }
}

// ---------------- per-(b,n) scans ------------------------------------------
__global__ __launch_bounds__(256) void scan_kernel(
    const float* __restrict__ fg, const float* __restrict__ ig,
    float* __restrict__ lfc, float* __restrict__ g, float* __restrict__ Mb) {
  __shared__ float sd[256];
  const int bn = blockIdx.x;
  const int tid = threadIdx.x;
  const float* fgp = &fg[(size_t)bn * S_];
  const float* igp = &ig[(size_t)bn * S_];
  float lf[4];
#pragma unroll
  for (int i = 0; i < 4; ++i) {
    const float f = fgp[tid * 4 + i];
    lf[i] = (f >= 0.f) ? -log1pf(expf(-f)) : (f - log1pf(expf(f)));
  }
  float p[4];
  p[0] = lf[0]; p[1] = p[0] + lf[1]; p[2] = p[1] + lf[2]; p[3] = p[2] + lf[3];
  sd[tid] = p[3];
  __syncthreads();
  for (int off = 1; off < 256; off <<= 1) {
    const float v = (tid >= off) ? sd[tid - off] : 0.f;
    __syncthreads();
    sd[tid] += v;
    __syncthreads();
  }
  const float excl = sd[tid] - p[3];
  float l[4];
#pragma unroll
  for (int i = 0; i < 4; ++i) {
    l[i] = excl + p[i];
    lfc[(size_t)bn * S_ + tid * 4 + i] = l[i];
  }
  float gv[4], pm[4];
#pragma unroll
  for (int i = 0; i < 4; ++i) gv[i] = igp[tid * 4 + i] - l[i];
  pm[0] = gv[0];
#pragma unroll
  for (int i = 1; i < 4; ++i) pm[i] = fmaxf(pm[i - 1], gv[i]);
  __syncthreads();
  sd[tid] = pm[3];
  __syncthreads();
  for (int off = 1; off < 256; off <<= 1) {
    const float v = (tid >= off) ? sd[tid - off] : -INFINITY;
    __syncthreads();
    sd[tid] = fmaxf(sd[tid], v);
    __syncthreads();
  }
  const float exclm = (tid > 0) ? sd[tid - 1] : -INFINITY;
#pragma unroll
  for (int i = 0; i < 4; ++i) {
    g[(size_t)bn * S_ + tid * 4 + i] = gv[i];
    Mb[(size_t)bn * S_ + tid * 4 + i] = fmaxf(exclm, pm[i]);
  }
}

// ---------------- mLSTM core: bf16 MFMA, 2-phase pipelined K/V -------------
__global__ __launch_bounds__(256) void mlstm_mfma(
    const ushort_t* __restrict__ qg, const ushort_t* __restrict__ kg,
    const ushort_t* __restrict__ vtg,
    const float* __restrict__ gb, const float* __restrict__ Mb, const float* __restrict__ lfc,
    float* __restrict__ hb) {
  __shared__ __align__(16) ushort_t Qs[64 * 96];
  __shared__ __align__(16) ushort_t Ks[2][64 * 96];
  __shared__ __align__(16) ushort_t Vt[2][80 * 64];   // [d][t], XOR-16B swizzled
  __shared__ __align__(16) ushort_t Ps[64 * 72];
  __shared__ float Ms_s[64], en_s[64];
  const int xb = blockIdx.x;
  const int pp = xb >> 1, odd = xb & 1;
  const int bn = pp >> 3, jj0 = pp & 7;
  const int st = odd ? (15 - jj0) : jj0;   // balanced pairing
  const int s0 = st << 6;
  const int tid = threadIdx.x, lane = tid & 63, wv = tid >> 6;
  const int cl = lane & 15, rowb = lane >> 4;
  const ushort_t* qb = qg + (size_t)bn * 1024 * 96;
  const ushort_t* kb = kg + (size_t)bn * 1024 * 96;
  const char* vtb = (const char*)(vtg + (size_t)bn * 72 * 1024);

  auto stage_kv = [&](int buf, int t0) {
    for (int i = wv; i < 21; i += 4) {
      if (i < 12) {
        gl16(kb + (size_t)t0 * 96 + i * 512 + lane * 8, &Ks[buf][i * 512]);
      } else {
        const int j = i - 12;
        const int o = j * 1024 + lane * 16;     // linear dest byte
        const int d = o >> 7;
        const int c = o & 127;
        const int ct = c ^ ((d & 7) << 4);      // inverse-swizzled source
        gl16(vtb + (size_t)d * 2048 + t0 * 2 + ct, (char*)&Vt[buf][0] + j * 1024);
      }
    }
  };

  // prologue: stage Q + tile 0; ones-col; row stats
  for (int i = wv; i < 12; i += 4)
    gl16(qb + (size_t)s0 * 96 + i * 512 + lane * 8, Qs + i * 512);
  stage_kv(0, 0);
  if (tid < 64) {
    const float m = Mb[bn * S_ + s0 + tid];
    Ms_s[tid] = m;
    en_s[tid] = __expf(-(lfc[bn * S_ + s0 + tid] + m));
  }
#pragma unroll
  for (int buf = 0; buf < 2; ++buf) {
    Vt[buf][72 * 64 + tid] = (tid < 64) ? (ushort_t)0x3F80 : (ushort_t)0;
    Vt[buf][72 * 64 + 256 + tid] = 0;
  }
  f32x4 accv[5];
#pragma unroll
  for (int n0 = 0; n0 < 5; ++n0) accv[n0] = (f32x4){0.f, 0.f, 0.f, 0.f};
  const float rsc = 0.11785113019775793f;   // 1/sqrt(72)
  __syncthreads();                          // Q + tile0 + init visible

  for (int tt = 0; tt <= st; ++tt) {
    const int cur = tt & 1;
    if (tt < st) stage_kv(cur ^ 1, (tt + 1) << 6);   // async prefetch
    const int t0 = tt << 6;
    // ---- QK^T: 4 tiles of 16x16, K=96 (cols 72..95 are zero) ----
    f32x4 qk[4];
#pragma unroll
    for (int n0 = 0; n0 < 4; ++n0) qk[n0] = (f32x4){0.f, 0.f, 0.f, 0.f};
#pragma unroll
    for (int k0 = 0; k0 < 96; k0 += 32) {
      const bf16x8 a = *(const bf16x8*)&Qs[(16 * wv + cl) * 96 + k0 + rowb * 8];
#pragma unroll
      for (int n0 = 0; n0 < 4; ++n0) {
        const bf16x8 b = *(const bf16x8*)&Ks[cur][(n0 * 16 + cl) * 96 + k0 + rowb * 8];
        qk[n0] = __builtin_amdgcn_mfma_f32_16x16x32_bf16(a, b, qk[n0], 0, 0, 0);
      }
    }
    // ---- decay weight + causal mask -> Ps (bf16, wave-private rows) ----
#pragma unroll
    for (int n0 = 0; n0 < 4; ++n0) {
      const int tc = t0 + n0 * 16 + cl;
      const float gtv = gb[bn * S_ + tc];
#pragma unroll
      for (int i = 0; i < 4; ++i) {
        const int srl = 16 * wv + 4 * rowb + i;
        const int sr = s0 + srl;
        const float w = (tc <= sr) ? qk[n0][i] * rsc * __expf(gtv - Ms_s[srl]) : 0.f;
        Ps[srl * 72 + n0 * 16 + cl] = f2bf(w);
      }
    }
    // ---- PV: 5 tiles of 16x16 over d (incl. ones-col), K=64 ----
#pragma unroll
    for (int k0 = 0; k0 < 64; k0 += 32) {
      const bf16x8 a = *(const bf16x8*)&Ps[(16 * wv + cl) * 72 + k0 + rowb * 8];
#pragma unroll
      for (int n0 = 0; n0 < 5; ++n0) {
        const int d = n0 * 16 + cl;
        const int ct0 = (k0 + rowb * 8) * 2;
        const int addr = d * 128 + (ct0 ^ ((d & 7) << 4));
        const bf16x8 b = *(const bf16x8*)((const char*)&Vt[cur][0] + addr);
        accv[n0] = __builtin_amdgcn_mfma_f32_16x16x32_bf16(a, b, accv[n0], 0, 0, 0);
      }
    }
    __syncthreads();    // drains prefetch vmcnt; next buf ready, cur reusable
  }
  // ---- epilogue: rowsum col (d=72) -> normalizer -> store ----
  float inv[4];
#pragma unroll
  for (int i = 0; i < 4; ++i) {
    const float rs = __shfl(accv[4][i], (lane & 48) + 8, 64);
    const int srl = 16 * wv + 4 * rowb + i;
    inv[i] = 1.f / (fmaxf(fabsf(rs), en_s[srl]) + 1e-6f);
  }
  float* hp = hb + ((size_t)bn * S_ + s0) * DHM_;
#pragma unroll
  for (int n0 = 0; n0 < 5; ++n0) {
    const int d = n0 * 16 + cl;
    if (d < 72) {
#pragma unroll
      for (int i = 0; i < 4; ++i) {
        const int srl = 16 * wv + 4 * rowb + i;
        hp[(size_t)srl * DHM_ + d] = accv[n0][i] * inv[i];
      }
    }
  }
}

// ---------------- headwise LN + skip + silu(z) gate ------------------------
__global__ __launch_bounds__(256) void ln_fuse_kernel(
    const float* __restrict__ hb, const float* __restrict__ xa, const float* __restrict__ y,
    const float* __restrict__ normw, const float* __restrict__ skipw,
    float* __restrict__ hstate) {
  const int gw = (blockIdx.x * 256 + threadIdx.x) >> 6;   // (b*S+s)*4 + n
  const int lane = threadIdx.x & 63;
  const int n = gw & 3;
  const int p = gw >> 2;
  const int b = p >> 10, s = p & 1023;
  const float* hp = hb + (((size_t)b * NHM_ + n) * S_ + s) * DHM_;
  const float x1 = hp[lane];
  const float x2 = (lane < 8) ? hp[64 + lane] : 0.f;
  float sum = x1 + x2;
#pragma unroll
  for (int off = 32; off >= 1; off >>= 1) sum += __shfl_xor(sum, off);
  const float mean = sum * (1.f / 72.f);
  const float d1 = x1 - mean;
  const float d2 = (lane < 8) ? (x2 - mean) : 0.f;
  float ss = d1 * d1 + d2 * d2;
#pragma unroll
  for (int off = 32; off >= 1; off >>= 1) ss += __shfl_xor(ss, off);
  const float inv = rsqrtf(ss * (1.f / 72.f) + 1e-5f);
  {
    const int c = n * DHM_ + lane;
    const float hn = d1 * inv * normw[c];
    const float xav = xa[(size_t)p * INNER_ + c];
    const float z = y[(size_t)p * 576 + 288 + c];
    const float sz = z / (1.f + expf(-z));
    hstate[(size_t)p * INNER_ + c] = (hn + skipw[c] * xav) * sz;
  }
  if (lane < 8) {
    const int c = n * DHM_ + 64 + lane;
    const float hn = d2 * inv * normw[c];
    const float xav = xa[(size_t)p * INNER_ + c];
    const float z = y[(size_t)p * 576 + 288 + c];
    const float sz = z / (1.f + expf(-z));
    hstate[(size_t)p * INNER_ + c] = (hn + skipw[c] * xav) * sz;
  }
}

extern "C" void kernel_launch(void* const* d_in, const int* in_sizes, int n_in,
                              void* d_out, int out_size, void* d_ws, size_t ws_size,
                              hipStream_t stream) {
  const float* x           = (const float*)d_in[0];
  const float* proj_up_w   = (const float*)d_in[1];
  const float* q_w         = (const float*)d_in[2];
  const float* k_w         = (const float*)d_in[3];
  const float* v_w         = (const float*)d_in[4];
  const float* conv_w      = (const float*)d_in[5];
  const float* ig_w        = (const float*)d_in[6];
  const float* ig_b        = (const float*)d_in[7];
  const float* fg_w        = (const float*)d_in[8];
  const float* fg_b        = (const float*)d_in[9];
  const float* norm_w      = (const float*)d_in[10];
  const float* skipw       = (const float*)d_in[11];
  const float* proj_down_w = (const float*)d_in[12];
  float* out = (float*)d_out;

  float* ws = (float*)d_ws;
  float* y      = ws;                            // 8192*576
  float* xa     = y      + (size_t)8192 * 576;   // 8192*288
  float* igb_   = xa     + (size_t)8192 * 288;   // 32768
  float* fgb_   = igb_   + 32768;
  float* lfcb   = fgb_   + 32768;
  float* gbuf   = lfcb   + 32768;
  float* Mbuf   = gbuf   + 32768;
  float* hbuf   = Mbuf   + 32768;                // 8192*288
  float* hstate = hbuf   + (size_t)8192 * 288;   // 8192*288
  ushort_t* qg  = (ushort_t*)(hstate + (size_t)8192 * 288);  // 32*1024*96
  ushort_t* kg  = qg + (size_t)32 * 1024 * 96;
  ushort_t* vg  = kg + (size_t)32 * 1024 * 96;               // 32*1024*72
  ushort_t* vtg = vg + (size_t)32 * 1024 * 72;               // 32*72*1024

  // 1. proj_up (bf16 MFMA, fp32 in/out)
  gemm_mfma_bt<64, 96, 192, 1><<<dim3(6, 128), 256, 0, stream>>>(x, proj_up_w, y, 8192, 576, 192);
  // 2. conv + silu
  conv_silu_kernel<<<(8192 * 288) / 256, 256, 0, stream>>>(y, conv_w, xa);
  // 3. headwise -> bf16 q/k (pitch 96) + v
  headwise_kernel<<<(32 * 1024 * 96) / 256, 256, 0, stream>>>(y, xa, q_w, k_w, v_w, qg, kg, vg);
  // 4. V transpose -> [bn][72][1024]
  vtrans_kernel<<<512, 256, 0, stream>>>(vg, vtg);
  // 5. gates
  gates_kernel<<<8192 / 4, 256, 0, stream>>>(qg, kg, vg, ig_w, ig_b, fg_w, fg_b, igb_, fgb_);
  // 6. scans
  scan_kernel<<<B_ * NHM_, 256, 0, stream>>>(fgb_, igb_, lfcb, gbuf, Mbuf);
  // 7. mLSTM core (bf16 MFMA, 2-phase)
  mlstm_mfma<<<512, 256, 0, stream>>>(qg, kg, vtg, gbuf, Mbuf, lfcb, hbuf);
  // 8. LN + skip + silu(z)
  ln_fuse_kernel<<<(8192 * 4) / 4, 256, 0, stream>>>(hbuf, xa, y, norm_w, skipw, hstate);
  // 9. proj_down (bf16 MFMA, fp32 in/out)
  gemm_mfma_bt<64, 96, 96, 3><<<dim3(2, 128), 256, 0, stream>>>(hstate, proj_down_w, out, 8192, 192, 288);
}

// Round 6
// 182.988 us; speedup vs baseline: 3.4264x; 1.1593x over previous
//
#include <hip/hip_runtime.h>
#include <math.h>

#define B_ 8
#define S_ 1024
#define INNER_ 288
#define NHM_ 4
#define DHM_ 72
#define H_ 32
#define W_ 32

typedef unsigned short ushort_t;
typedef unsigned int uint_t;
typedef __bf16 bf16x8 __attribute__((ext_vector_type(8)));
typedef float f32x4 __attribute__((ext_vector_type(4)));

__device__ __forceinline__ ushort_t f2bf(float f) {
  union { float f; unsigned u; } v; v.f = f;
  unsigned r = v.u + 0x7FFF + ((v.u >> 16) & 1);
  return (ushort_t)(r >> 16);
}
__device__ __forceinline__ float bf2f(ushort_t u) {
  union { unsigned u; float f; } v; v.u = ((unsigned)u) << 16;
  return v.f;
}
__device__ __forceinline__ void gl16(const void* g, void* l) {
  __builtin_amdgcn_global_load_lds(
      (const __attribute__((address_space(1))) void*)g,
      (__attribute__((address_space(3))) void*)l, 16, 0, 0);
}

// ---------------- fp32 -> swizzled bf16 (pitch KPAD, 64-col tiles) ---------
// layout: dst[m*KPAD + (k&~63) + ((k&63) ^ ((m&7)<<3))]
__global__ __launch_bounds__(256) void cvt_swz_kernel(
    const float* __restrict__ src, ushort_t* __restrict__ dst, int K, int KPAD) {
  const int idx = blockIdx.x * 256 + threadIdx.x;
  const int k = idx % KPAD, m = idx / KPAD;
  const float v = (k < K) ? src[(size_t)m * K + k] : 0.f;
  dst[(size_t)m * KPAD + (k & ~63) + ((k & 63) ^ ((m & 7) << 3))] = f2bf(v);
}

// ---------------- bf16 MFMA GEMM: C[M,N] = A[M,K] @ B[N,K]^T ----------------
// A,B pre-swizzled bf16 (pitch KT*64); BM=128, BN=64, BK=64, double-buffered.
template<int KT>
__global__ __launch_bounds__(256) void gemm_bf16(
    const ushort_t* __restrict__ A, const ushort_t* __restrict__ Bw,
    float* __restrict__ C, int N) {
  __shared__ __align__(16) ushort_t As[2][128 * 64];
  __shared__ __align__(16) ushort_t Bs[2][64 * 64];
  const int tid = threadIdx.x, lane = tid & 63, wv = tid >> 6;
  const int wm = wv >> 1, wn = wv & 1;
  const int cl = lane & 15, rowb = lane >> 4;
  const int m0 = blockIdx.y * 128, n0 = blockIdx.x * 64;
  const char* Ab = (const char*)A;
  const char* Bb = (const char*)Bw;

  auto stage = [&](int buf, int kt) {
    for (int u = wv; u < 24; u += 4) {
      if (u < 16) {
        const int o = u * 1024 + lane * 16;
        const int r = o >> 7, c = o & 127;
        gl16(Ab + ((size_t)(m0 + r) * KT + kt) * 128 + c, (char*)As[buf] + u * 1024);
      } else {
        const int o = (u - 16) * 1024 + lane * 16;
        const int r = o >> 7, c = o & 127;
        gl16(Bb + ((size_t)(n0 + r) * KT + kt) * 128 + c, (char*)Bs[buf] + (u - 16) * 1024);
      }
    }
  };

  f32x4 acc[4][2];
#pragma unroll
  for (int mi = 0; mi < 4; ++mi)
#pragma unroll
    for (int nj = 0; nj < 2; ++nj) acc[mi][nj] = (f32x4){0.f, 0.f, 0.f, 0.f};

  stage(0, 0);
  __syncthreads();
  for (int kt = 0; kt < KT; ++kt) {
    const int cur = kt & 1;
    if (kt + 1 < KT) stage(cur ^ 1, kt + 1);
#pragma unroll
    for (int ks = 0; ks < 2; ++ks) {
      bf16x8 af[4], bfr[2];
#pragma unroll
      for (int mi = 0; mi < 4; ++mi) {
        const int row = wm * 64 + mi * 16 + cl;
        af[mi] = *(const bf16x8*)((const char*)As[cur] + row * 128 +
                                  ((2 * (ks * 32 + rowb * 8)) ^ ((row & 7) << 4)));
      }
#pragma unroll
      for (int nj = 0; nj < 2; ++nj) {
        const int row = wn * 32 + nj * 16 + cl;
        bfr[nj] = *(const bf16x8*)((const char*)Bs[cur] + row * 128 +
                                   ((2 * (ks * 32 + rowb * 8)) ^ ((row & 7) << 4)));
      }
#pragma unroll
      for (int mi = 0; mi < 4; ++mi)
#pragma unroll
        for (int nj = 0; nj < 2; ++nj)
          acc[mi][nj] = __builtin_amdgcn_mfma_f32_16x16x32_bf16(af[mi], bfr[nj], acc[mi][nj], 0, 0, 0);
    }
    __syncthreads();
  }
#pragma unroll
  for (int mi = 0; mi < 4; ++mi)
#pragma unroll
    for (int i = 0; i < 4; ++i) {
      const size_t m = m0 + wm * 64 + mi * 16 + rowb * 4 + i;
#pragma unroll
      for (int nj = 0; nj < 2; ++nj)
        C[m * N + n0 + wn * 32 + nj * 16 + cl] = acc[mi][nj][i];
    }
}

// ---------------- depthwise 3x3 conv (SAME) + SiLU, float4 -----------------
__global__ __launch_bounds__(256) void conv_silu_kernel(
    const float* __restrict__ y, const float* __restrict__ cw, float* __restrict__ xa) {
  const int idx = blockIdx.x * 256 + threadIdx.x;   // over B*S*72
  const int c4 = idx % 72;
  const int p = idx / 72;
  const int c = c4 * 4;
  const int xx = p & 31, yy = (p >> 5) & 31, b = p >> 10;
  float4 acc = {0.f, 0.f, 0.f, 0.f};
#pragma unroll
  for (int ky = 0; ky < 3; ++ky) {
    const int iy = yy + ky - 1;
    if (iy < 0 || iy >= H_) continue;
#pragma unroll
    for (int kx = 0; kx < 3; ++kx) {
      const int ix = xx + kx - 1;
      if (ix < 0 || ix >= W_) continue;
      const float4 v = *(const float4*)&y[((size_t)((b << 10) + (iy << 5) + ix)) * 576 + c];
      const float4 w = *(const float4*)&cw[(ky * 3 + kx) * INNER_ + c];
      acc.x += v.x * w.x; acc.y += v.y * w.y; acc.z += v.z * w.z; acc.w += v.w * w.w;
    }
  }
  float4 o;
  o.x = acc.x / (1.f + __expf(-acc.x));
  o.y = acc.y / (1.f + __expf(-acc.y));
  o.z = acc.z / (1.f + __expf(-acc.z));
  o.w = acc.w / (1.f + __expf(-acc.w));
  *(float4*)&xa[(size_t)p * INNER_ + c] = o;
}

// ---------------- headwise q/k/v -> swizzled bf16 (q,k pitch 128) ----------
__global__ __launch_bounds__(256) void headwise_kernel(
    const float* __restrict__ y, const float* __restrict__ xa,
    const float* __restrict__ qw, const float* __restrict__ kw, const float* __restrict__ vw,
    ushort_t* __restrict__ qg, ushort_t* __restrict__ kg, ushort_t* __restrict__ vg) {
  const int idx = blockIdx.x * 256 + threadIdx.x;   // 32*1024 rows x 32 slots
  const int g = idx & 31, r = idx >> 5;             // r = bn*1024 + s
  const int s = r & 1023, bn = r >> 10, b = bn >> 2, n = bn & 3;
  const int swz = (r & 7) << 3;
  ushort_t* qrow = qg + (size_t)r * 128;
  ushort_t* krow = kg + (size_t)r * 128;
  if (g >= 18) {   // zero-fill logical d in [72,128)
    const int d0 = 72 + (g - 18) * 4;
    const ushort4 z = {0, 0, 0, 0};
    *(ushort4*)&qrow[d0 ^ swz] = z;
    *(ushort4*)&krow[d0 ^ swz] = z;
    return;
  }
  const int hq = n * 18 + g;
  const int p = (b << 10) + s;
  const float4 xav = *(const float4*)&xa[(size_t)p * INNER_ + hq * 4];
  const float4 xmv = *(const float4*)&y[(size_t)p * 576 + hq * 4];
  float q[4], k2[4], v[4];
#pragma unroll
  for (int o = 0; o < 4; ++o) {
    const float4 wq = *(const float4*)&qw[hq * 16 + o * 4];
    const float4 wk = *(const float4*)&kw[hq * 16 + o * 4];
    const float4 wv4 = *(const float4*)&vw[hq * 16 + o * 4];
    q[o]  = wq.x * xav.x + wq.y * xav.y + wq.z * xav.z + wq.w * xav.w;
    k2[o] = wk.x * xav.x + wk.y * xav.y + wk.z * xav.z + wk.w * xav.w;
    v[o]  = wv4.x * xmv.x + wv4.y * xmv.y + wv4.z * xmv.z + wv4.w * xmv.w;
  }
  ushort4 uq = {f2bf(q[0]), f2bf(q[1]), f2bf(q[2]), f2bf(q[3])};
  ushort4 uk = {f2bf(k2[0]), f2bf(k2[1]), f2bf(k2[2]), f2bf(k2[3])};
  ushort4 uv = {f2bf(v[0]), f2bf(v[1]), f2bf(v[2]), f2bf(v[3])};
  *(ushort4*)&qrow[(g * 4) ^ swz] = uq;
  *(ushort4*)&krow[(g * 4) ^ swz] = uk;
  *(ushort4*)&vg[(size_t)r * 72 + g * 4] = uv;
}

// ---------------- V transpose -> per-tile swizzled [bn][tt][80x64] ---------
__global__ __launch_bounds__(256) void vtrans_kernel(
    const ushort_t* __restrict__ vg, ushort_t* __restrict__ vtg) {
  __shared__ ushort_t T[64][82];
  const int bn = blockIdx.x >> 4, tt = blockIdx.x & 15;
  const int s0 = tt << 6, tid = threadIdx.x;
  const uint_t* v32 = (const uint_t*)vg;
  for (int i = tid; i < 64 * 36; i += 256) {
    const int rr = i / 36, c2 = i % 36;
    *(uint_t*)&T[rr][c2 * 2] = v32[((size_t)(bn * 1024 + s0 + rr)) * 36 + c2];
  }
  __syncthreads();
  char* outb = (char*)(vtg + ((size_t)(bn * 16 + tt)) * 5120);
  for (int i = tid; i < 80 * 32; i += 256) {
    const int d = i >> 5, m = i & 31;
    uint_t val;
    if (d < 72) val = (uint_t)T[2 * m][d] | ((uint_t)T[2 * m + 1][d] << 16);
    else val = (d == 72) ? 0x3F803F80u : 0u;   // ones row / zero pad
    *(uint_t*)(outb + d * 128 + ((m * 4) ^ ((d & 7) << 4))) = val;
  }
}

// ---------------- gates (swizzled bf16 q/k, plain v) -----------------------
__global__ __launch_bounds__(256) void gates_kernel(
    const ushort_t* __restrict__ qg, const ushort_t* __restrict__ kg, const ushort_t* __restrict__ vg,
    const float* __restrict__ igw, const float* __restrict__ igb,
    const float* __restrict__ fgw, const float* __restrict__ fgb,
    float* __restrict__ ig, float* __restrict__ fg) {
  const int gw = (blockIdx.x * 256 + threadIdx.x) >> 6;  // b*S+s
  const int lane = threadIdx.x & 63;
  const int b = gw >> 10, s = gw & 1023;
  float iacc[4] = {}, facc[4] = {};
  for (int j = lane; j < 864; j += 64) {
    const int part = j / INNER_;
    const int c = j - part * INNER_;
    const int n = c / DHM_, d = c % DHM_;
    const size_t row = (size_t)(b * 4 + n) * 1024 + s;
    ushort_t u;
    if (part == 2)      u = vg[row * 72 + d];
    else {
      const size_t si = row * 128 + (d ^ ((row & 7) << 3));
      u = (part == 0) ? qg[si] : kg[si];
    }
    const float gv = bf2f(u);
#pragma unroll
    for (int nn = 0; nn < 4; ++nn) {
      iacc[nn] += gv * igw[nn * 864 + j];
      facc[nn] += gv * fgw[nn * 864 + j];
    }
  }
#pragma unroll
  for (int off = 32; off >= 1; off >>= 1) {
#pragma unroll
    for (int nn = 0; nn < 4; ++nn) {
      iacc[nn] += __shfl_xor(iacc[nn], off);
      facc[nn] += __shfl_xor(facc[nn], off);
    }
  }
  if (lane == 0) {
#pragma unroll
    for (int nn = 0; nn < 4; ++nn) {
      ig[((size_t)b * NHM_ + nn) * S_ + s] = iacc[nn] + igb[nn];
      fg[((size_t)b * NHM_ + nn) * S_ + s] = facc[nn] + fgb[nn];
    }
  }
}

// ---------------- per-(b,n) scans ------------------------------------------
__global__ __launch_bounds__(256) void scan_kernel(
    const float* __restrict__ fg, const float* __restrict__ ig,
    float* __restrict__ lfc, float* __restrict__ g, float* __restrict__ Mb) {
  __shared__ float sd[256];
  const int bn = blockIdx.x;
  const int tid = threadIdx.x;
  const float* fgp = &fg[(size_t)bn * S_];
  const float* igp = &ig[(size_t)bn * S_];
  float lf[4];
#pragma unroll
  for (int i = 0; i < 4; ++i) {
    const float f = fgp[tid * 4 + i];
    lf[i] = (f >= 0.f) ? -log1pf(expf(-f)) : (f - log1pf(expf(f)));
  }
  float p[4];
  p[0] = lf[0]; p[1] = p[0] + lf[1]; p[2] = p[1] + lf[2]; p[3] = p[2] + lf[3];
  sd[tid] = p[3];
  __syncthreads();
  for (int off = 1; off < 256; off <<= 1) {
    const float v = (tid >= off) ? sd[tid - off] : 0.f;
    __syncthreads();
    sd[tid] += v;
    __syncthreads();
  }
  const float excl = sd[tid] - p[3];
  float l[4];
#pragma unroll
  for (int i = 0; i < 4; ++i) {
    l[i] = excl + p[i];
    lfc[(size_t)bn * S_ + tid * 4 + i] = l[i];
  }
  float gv[4], pm[4];
#pragma unroll
  for (int i = 0; i < 4; ++i) gv[i] = igp[tid * 4 + i] - l[i];
  pm[0] = gv[0];
#pragma unroll
  for (int i = 1; i < 4; ++i) pm[i] = fmaxf(pm[i - 1], gv[i]);
  __syncthreads();
  sd[tid] = pm[3];
  __syncthreads();
  for (int off = 1; off < 256; off <<= 1) {
    const float v = (tid >= off) ? sd[tid - off] : -INFINITY;
    __syncthreads();
    sd[tid] = fmaxf(sd[tid], v);
    __syncthreads();
  }
  const float exclm = (tid > 0) ? sd[tid - 1] : -INFINITY;
#pragma unroll
  for (int i = 0; i < 4; ++i) {
    g[(size_t)bn * S_ + tid * 4 + i] = gv[i];
    Mb[(size_t)bn * S_ + tid * 4 + i] = fmaxf(exclm, pm[i]);
  }
}

// ---------------- mLSTM core: bf16 MFMA, swizzled LDS, balanced ------------
__global__ __launch_bounds__(256) void mlstm_mfma(
    const ushort_t* __restrict__ qg, const ushort_t* __restrict__ kg,
    const ushort_t* __restrict__ vtg,
    const float* __restrict__ gb, const float* __restrict__ Mb, const float* __restrict__ lfc,
    float* __restrict__ hb) {
  __shared__ __align__(16) ushort_t Ks[2][64 * 128];
  __shared__ __align__(16) ushort_t Vt[2][80 * 64];
  __shared__ __align__(16) ushort_t Ps[64 * 72];
  __shared__ float gs[1024];
  __shared__ float Ms_s[64], en_s[64];
  // CU-balanced mapping: blocks i and i+256 share a CU (round-robin) and get
  // st pairs (j, 15-j) summing to 17 tiles, with the same bn (L2 reuse).
  const int bi = blockIdx.x;
  const int bn = bi & 31;
  const int j = (bi >> 5) & 7;
  const int st = (bi >> 8) ? (15 - j) : j;
  const int s0 = st << 6;
  const int tid = threadIdx.x, lane = tid & 63, wv = tid >> 6;
  const int cl = lane & 15, rowb = lane >> 4;
  const char* kb = (const char*)(kg + (size_t)bn * 1024 * 128);
  const char* vtb = (const char*)(vtg + (size_t)bn * 16 * 5120);

  auto stage = [&](int buf, int tt) {
    const char* ks = kb + (size_t)tt * (64 * 256);
    const char* vs = vtb + (size_t)tt * 10240;
    for (int u = wv; u < 26; u += 4) {
      if (u < 16) gl16(ks + u * 1024 + lane * 16, (char*)Ks[buf] + u * 1024);
      else        gl16(vs + (u - 16) * 1024 + lane * 16, (char*)Vt[buf] + (u - 16) * 1024);
    }
  };

  // prologue
  stage(0, 0);
  *(float4*)&gs[tid * 4] = *(const float4*)&gb[(size_t)bn * S_ + tid * 4];
  if (tid < 64) {
    const float m = Mb[(size_t)bn * S_ + s0 + tid];
    Ms_s[tid] = m;
    en_s[tid] = __expf(-(lfc[(size_t)bn * S_ + s0 + tid] + m));
  }
  // Q fragments -> registers (swizzled global read, once)
  const int qrow = bn * 1024 + s0 + 16 * wv + cl;
  const ushort_t* qp = qg + (size_t)qrow * 128;
  const int qx = (qrow & 7) << 3;
  bf16x8 qf[3];
#pragma unroll
  for (int kk = 0; kk < 3; ++kk) qf[kk] = *(const bf16x8*)&qp[(kk * 32 + rowb * 8) ^ qx];

  f32x4 accv[5];
#pragma unroll
  for (int n0 = 0; n0 < 5; ++n0) accv[n0] = (f32x4){0.f, 0.f, 0.f, 0.f};
  const float rsc = 0.11785113019775793f;   // 1/sqrt(72)
  const int srl0 = 16 * wv + 4 * rowb;
  __syncthreads();

  // off-diagonal tiles: no causal mask needed
  for (int tt = 0; tt < st; ++tt) {
    const int cur = tt & 1;
    stage(cur ^ 1, tt + 1);
    const int t0 = tt << 6;
    f32x4 qk[4];
#pragma unroll
    for (int n0 = 0; n0 < 4; ++n0) qk[n0] = (f32x4){0.f, 0.f, 0.f, 0.f};
#pragma unroll
    for (int kk = 0; kk < 3; ++kk) {
#pragma unroll
      for (int n0 = 0; n0 < 4; ++n0) {
        const int rl = n0 * 16 + cl;
        const bf16x8 b = *(const bf16x8*)((const char*)Ks[cur] + rl * 256 +
                                          ((2 * (kk * 32 + rowb * 8)) ^ ((rl & 7) << 4)));
        qk[n0] = __builtin_amdgcn_mfma_f32_16x16x32_bf16(qf[kk], b, qk[n0], 0, 0, 0);
      }
    }
#pragma unroll
    for (int n0 = 0; n0 < 4; ++n0) {
      const float gtv = gs[t0 + n0 * 16 + cl];
#pragma unroll
      for (int i = 0; i < 4; ++i) {
        const float w = qk[n0][i] * rsc * __expf(gtv - Ms_s[srl0 + i]);
        Ps[(srl0 + i) * 72 + n0 * 16 + cl] = f2bf(w);
      }
    }
#pragma unroll
    for (int k0 = 0; k0 < 64; k0 += 32) {
      const bf16x8 a = *(const bf16x8*)&Ps[(16 * wv + cl) * 72 + k0 + rowb * 8];
#pragma unroll
      for (int n0 = 0; n0 < 5; ++n0) {
        const int d = n0 * 16 + cl;
        const bf16x8 b = *(const bf16x8*)((const char*)Vt[cur] + d * 128 +
                                          ((2 * (k0 + rowb * 8)) ^ ((d & 7) << 4)));
        accv[n0] = __builtin_amdgcn_mfma_f32_16x16x32_bf16(a, b, accv[n0], 0, 0, 0);
      }
    }
    __syncthreads();
  }
  // diagonal tile (causal mask)
  {
    const int cur = st & 1;
    f32x4 qk[4];
#pragma unroll
    for (int n0 = 0; n0 < 4; ++n0) qk[n0] = (f32x4){0.f, 0.f, 0.f, 0.f};
#pragma unroll
    for (int kk = 0; kk < 3; ++kk) {
#pragma unroll
      for (int n0 = 0; n0 < 4; ++n0) {
        const int rl = n0 * 16 + cl;
        const bf16x8 b = *(const bf16x8*)((const char*)Ks[cur] + rl * 256 +
                                          ((2 * (kk * 32 + rowb * 8)) ^ ((rl & 7) << 4)));
        qk[n0] = __builtin_amdgcn_mfma_f32_16x16x32_bf16(qf[kk], b, qk[n0], 0, 0, 0);
      }
    }
#pragma unroll
    for (int n0 = 0; n0 < 4; ++n0) {
      const int tc = n0 * 16 + cl;
      const float gtv = gs[s0 + tc];
#pragma unroll
      for (int i = 0; i < 4; ++i) {
        const int srl = srl0 + i;
        const float w = (tc <= srl) ? qk[n0][i] * rsc * __expf(gtv - Ms_s[srl]) : 0.f;
        Ps[srl * 72 + n0 * 16 + cl] = f2bf(w);
      }
    }
#pragma unroll
    for (int k0 = 0; k0 < 64; k0 += 32) {
      const bf16x8 a = *(const bf16x8*)&Ps[(16 * wv + cl) * 72 + k0 + rowb * 8];
#pragma unroll
      for (int n0 = 0; n0 < 5; ++n0) {
        const int d = n0 * 16 + cl;
        const bf16x8 b = *(const bf16x8*)((const char*)Vt[cur] + d * 128 +
                                          ((2 * (k0 + rowb * 8)) ^ ((d & 7) << 4)));
        accv[n0] = __builtin_amdgcn_mfma_f32_16x16x32_bf16(a, b, accv[n0], 0, 0, 0);
      }
    }
  }
  // epilogue: rowsum (d=72) -> normalizer -> store
  float inv[4];
#pragma unroll
  for (int i = 0; i < 4; ++i) {
    const float rs = __shfl(accv[4][i], (lane & 48) + 8, 64);
    inv[i] = 1.f / (fmaxf(fabsf(rs), en_s[srl0 + i]) + 1e-6f);
  }
  float* hp = hb + ((size_t)bn * S_ + s0) * DHM_;
#pragma unroll
  for (int n0 = 0; n0 < 5; ++n0) {
    const int d = n0 * 16 + cl;
    if (d < 72) {
#pragma unroll
      for (int i = 0; i < 4; ++i)
        hp[(size_t)(srl0 + i) * DHM_ + d] = accv[n0][i] * inv[i];
    }
  }
}

// ---------------- headwise LN + skip + silu(z) -> swizzled bf16 ------------
__global__ __launch_bounds__(256) void ln_fuse_kernel(
    const float* __restrict__ hb, const float* __restrict__ xa, const float* __restrict__ y,
    const float* __restrict__ normw, const float* __restrict__ skipw,
    ushort_t* __restrict__ hsb) {
  const int gw = (blockIdx.x * 256 + threadIdx.x) >> 6;   // (b*S+s)*4 + n
  const int lane = threadIdx.x & 63;
  const int n = gw & 3;
  const int p = gw >> 2;
  const int b = p >> 10, s = p & 1023;
  const int pswz = (p & 7) << 3;
  ushort_t* hrow = hsb + (size_t)p * 320;
  const float* hp = hb + (((size_t)b * NHM_ + n) * S_ + s) * DHM_;
  const float x1 = hp[lane];
  const float x2 = (lane < 8) ? hp[64 + lane] : 0.f;
  float sum = x1 + x2;
#pragma unroll
  for (int off = 32; off >= 1; off >>= 1) sum += __shfl_xor(sum, off);
  const float mean = sum * (1.f / 72.f);
  const float d1 = x1 - mean;
  const float d2 = (lane < 8) ? (x2 - mean) : 0.f;
  float ss = d1 * d1 + d2 * d2;
#pragma unroll
  for (int off = 32; off >= 1; off >>= 1) ss += __shfl_xor(ss, off);
  const float inv = rsqrtf(ss * (1.f / 72.f) + 1e-5f);
  {
    const int c = n * DHM_ + lane;
    const float hn = d1 * inv * normw[c];
    const float xav = xa[(size_t)p * INNER_ + c];
    const float z = y[(size_t)p * 576 + 288 + c];
    const float sz = z / (1.f + __expf(-z));
    hrow[(c & ~63) + ((c & 63) ^ pswz)] = f2bf((hn + skipw[c] * xav) * sz);
  }
  if (lane < 8) {
    const int c = n * DHM_ + 64 + lane;
    const float hn = d2 * inv * normw[c];
    const float xav = xa[(size_t)p * INNER_ + c];
    const float z = y[(size_t)p * 576 + 288 + c];
    const float sz = z / (1.f + __expf(-z));
    hrow[(c & ~63) + ((c & 63) ^ pswz)] = f2bf((hn + skipw[c] * xav) * sz);
  }
  if (n == 3 && lane >= 32) {   // zero-pad K to 320
    const int c = 288 + (lane - 32);
    hrow[256 + ((c & 63) ^ pswz)] = 0;
  }
}

extern "C" void kernel_launch(void* const* d_in, const int* in_sizes, int n_in,
                              void* d_out, int out_size, void* d_ws, size_t ws_size,
                              hipStream_t stream) {
  const float* x           = (const float*)d_in[0];
  const float* proj_up_w   = (const float*)d_in[1];
  const float* q_w         = (const float*)d_in[2];
  const float* k_w         = (const float*)d_in[3];
  const float* v_w         = (const float*)d_in[4];
  const float* conv_w      = (const float*)d_in[5];
  const float* ig_w        = (const float*)d_in[6];
  const float* ig_b        = (const float*)d_in[7];
  const float* fg_w        = (const float*)d_in[8];
  const float* fg_b        = (const float*)d_in[9];
  const float* norm_w      = (const float*)d_in[10];
  const float* skipw       = (const float*)d_in[11];
  const float* proj_down_w = (const float*)d_in[12];
  float* out = (float*)d_out;

  float* ws = (float*)d_ws;
  float* y      = ws;                            // 8192*576
  float* xa     = y      + (size_t)8192 * 576;   // 8192*288
  float* igb_   = xa     + (size_t)8192 * 288;   // 32768
  float* fgb_   = igb_   + 32768;
  float* lfcb   = fgb_   + 32768;
  float* gbuf   = lfcb   + 32768;
  float* Mbuf   = gbuf   + 32768;
  float* hbuf   = Mbuf   + 32768;                // 8192*288
  ushort_t* qg  = (ushort_t*)(hbuf + (size_t)8192 * 288);    // 32*1024*128
  ushort_t* kg  = qg  + (size_t)32 * 1024 * 128;
  ushort_t* vg  = kg  + (size_t)32 * 1024 * 128;             // 32*1024*72
  ushort_t* vtg = vg  + (size_t)32 * 1024 * 72;              // 32*16*5120
  ushort_t* xbf = vtg + (size_t)32 * 16 * 5120;              // 8192*192
  ushort_t* wup = xbf + (size_t)8192 * 192;                  // 576*192
  ushort_t* wdn = wup + (size_t)576 * 192;                   // 192*320
  ushort_t* hsb = wdn + (size_t)192 * 320;                   // 8192*320

  // 0. one-time (per launch) conversions to swizzled bf16
  cvt_swz_kernel<<<(8192 * 192) / 256, 256, 0, stream>>>(x, xbf, 192, 192);
  cvt_swz_kernel<<<(576 * 192) / 256, 256, 0, stream>>>(proj_up_w, wup, 192, 192);
  cvt_swz_kernel<<<(192 * 320) / 256, 256, 0, stream>>>(proj_down_w, wdn, 288, 320);
  // 1. proj_up: y = x @ proj_up_w^T (bf16 MFMA)
  gemm_bf16<3><<<dim3(9, 64), 256, 0, stream>>>(xbf, wup, y, 576);
  // 2. conv + silu
  conv_silu_kernel<<<(8192 * 72) / 256, 256, 0, stream>>>(y, conv_w, xa);
  // 3. headwise -> swizzled bf16 q/k (pitch 128) + v
  headwise_kernel<<<(32768 * 32) / 256, 256, 0, stream>>>(y, xa, q_w, k_w, v_w, qg, kg, vg);
  // 4. V transpose -> per-tile swizzled
  vtrans_kernel<<<512, 256, 0, stream>>>(vg, vtg);
  // 5. gates
  gates_kernel<<<8192 / 4, 256, 0, stream>>>(qg, kg, vg, ig_w, ig_b, fg_w, fg_b, igb_, fgb_);
  // 6. scans
  scan_kernel<<<B_ * NHM_, 256, 0, stream>>>(fgb_, igb_, lfcb, gbuf, Mbuf);
  // 7. mLSTM core
  mlstm_mfma<<<512, 256, 0, stream>>>(qg, kg, vtg, gbuf, Mbuf, lfcb, hbuf);
  // 8. LN + skip + silu(z) -> swizzled bf16 hstate (K padded to 320)
  ln_fuse_kernel<<<(8192 * 4) / 4, 256, 0, stream>>>(hbuf, xa, y, norm_w, skipw, hsb);
  // 9. proj_down (bf16 MFMA)
  gemm_bf16<5><<<dim3(3, 64), 256, 0, stream>>>(hsb, wdn, out, 192);
}

// Round 9
// 168.898 us; speedup vs baseline: 3.7122x; 1.0834x over previous
//
#include <hip/hip_runtime.h>
#include <math.h>

#define B_ 8
#define S_ 1024
#define INNER_ 288
#define NHM_ 4
#define DHM_ 72
#define H_ 32
#define W_ 32

typedef unsigned short ushort_t;
typedef unsigned int uint_t;
typedef __bf16 bf16x8 __attribute__((ext_vector_type(8)));
typedef float f32x4 __attribute__((ext_vector_type(4)));

__device__ __forceinline__ ushort_t f2bf(float f) {
  union { float f; unsigned u; } v; v.f = f;
  unsigned r = v.u + 0x7FFF + ((v.u >> 16) & 1);
  return (ushort_t)(r >> 16);
}
__device__ __forceinline__ float bf2f(ushort_t u) {
  union { unsigned u; float f; } v; v.u = ((unsigned)u) << 16;
  return v.f;
}
__device__ __forceinline__ void gl16(const void* g, void* l) {
  __builtin_amdgcn_global_load_lds(
      (const __attribute__((address_space(1))) void*)g,
      (__attribute__((address_space(3))) void*)l, 16, 0, 0);
}

// ---------------- prep: all fp32->swizzled-bf16 cvts + zero pads, 1 kernel --
// regions (ushort4 slots): xbf 393216 | wup 27648 | wdn 15360 |
//   hsb cols[256,320) zero 131072 | qg cols[64,128) zero 524288 | kg same
__global__ __launch_bounds__(256) void prep_kernel(
    const float* __restrict__ x, const float* __restrict__ wupf,
    const float* __restrict__ wdnf,
    ushort_t* __restrict__ xbf, ushort_t* __restrict__ wup, ushort_t* __restrict__ wdn,
    ushort_t* __restrict__ hsb, ushort_t* __restrict__ qg, ushort_t* __restrict__ kg) {
  int s4 = blockIdx.x * 256 + threadIdx.x;
  const ushort4 z4 = {0, 0, 0, 0};
  if (s4 < 393216) {           // xbf: 8192x192, K=192
    const int m = s4 / 48, k4 = (s4 % 48) * 4;
    const float4 v = *(const float4*)&x[(size_t)m * 192 + k4];
    ushort4 w = {f2bf(v.x), f2bf(v.y), f2bf(v.z), f2bf(v.w)};
    *(ushort4*)&xbf[(size_t)m * 192 + (k4 & ~63) + ((k4 & 63) ^ ((m & 7) << 3))] = w;
    return;
  }
  s4 -= 393216;
  if (s4 < 27648) {            // wup: 576x192, K=192
    const int m = s4 / 48, k4 = (s4 % 48) * 4;
    const float4 v = *(const float4*)&wupf[(size_t)m * 192 + k4];
    ushort4 w = {f2bf(v.x), f2bf(v.y), f2bf(v.z), f2bf(v.w)};
    *(ushort4*)&wup[(size_t)m * 192 + (k4 & ~63) + ((k4 & 63) ^ ((m & 7) << 3))] = w;
    return;
  }
  s4 -= 27648;
  if (s4 < 15360) {            // wdn: 192x320, K=288
    const int m = s4 / 80, k4 = (s4 % 80) * 4;
    ushort4 w = z4;
    if (k4 < 288) {
      const float4 v = *(const float4*)&wdnf[(size_t)m * 288 + k4];
      w = (ushort4){f2bf(v.x), f2bf(v.y), f2bf(v.z), f2bf(v.w)};
    }
    *(ushort4*)&wdn[(size_t)m * 320 + (k4 & ~63) + ((k4 & 63) ^ ((m & 7) << 3))] = w;
    return;
  }
  s4 -= 15360;
  if (s4 < 131072) {           // hsb rows 8192, cols [256,320) zero
    const int p = s4 >> 4, j = s4 & 15;
    *(ushort4*)&hsb[(size_t)p * 320 + 256 + j * 4] = z4;
    return;
  }
  s4 -= 131072;
  if (s4 < 524288) {           // qg rows 32768, cols [64,128) zero
    const int r = s4 >> 4, j = s4 & 15;
    *(ushort4*)&qg[(size_t)r * 128 + 64 + j * 4] = z4;
    return;
  }
  s4 -= 524288;
  {                            // kg rows 32768, cols [64,128) zero
    const int r = s4 >> 4, j = s4 & 15;
    *(ushort4*)&kg[(size_t)r * 128 + 64 + j * 4] = z4;
  }
}

// ---------------- bf16 MFMA GEMM: C[M,N] = A[M,K] @ B[N,K]^T ----------------
// A,B pre-swizzled bf16 (pitch KT*64); BM=128, BN=64, BK=64, double-buffered.
template<int KT>
__global__ __launch_bounds__(256) void gemm_bf16(
    const ushort_t* __restrict__ A, const ushort_t* __restrict__ Bw,
    float* __restrict__ C, int N) {
  __shared__ __align__(16) ushort_t As[2][128 * 64];
  __shared__ __align__(16) ushort_t Bs[2][64 * 64];
  const int tid = threadIdx.x, lane = tid & 63, wv = tid >> 6;
  const int wm = wv >> 1, wn = wv & 1;
  const int cl = lane & 15, rowb = lane >> 4;
  const int m0 = blockIdx.y * 128, n0 = blockIdx.x * 64;
  const char* Ab = (const char*)A;
  const char* Bb = (const char*)Bw;

  auto stage = [&](int buf, int kt) {
    for (int u = wv; u < 24; u += 4) {
      if (u < 16) {
        const int o = u * 1024 + lane * 16;
        const int r = o >> 7, c = o & 127;
        gl16(Ab + ((size_t)(m0 + r) * KT + kt) * 128 + c, (char*)As[buf] + u * 1024);
      } else {
        const int o = (u - 16) * 1024 + lane * 16;
        const int r = o >> 7, c = o & 127;
        gl16(Bb + ((size_t)(n0 + r) * KT + kt) * 128 + c, (char*)Bs[buf] + (u - 16) * 1024);
      }
    }
  };

  f32x4 acc[4][2];
#pragma unroll
  for (int mi = 0; mi < 4; ++mi)
#pragma unroll
    for (int nj = 0; nj < 2; ++nj) acc[mi][nj] = (f32x4){0.f, 0.f, 0.f, 0.f};

  stage(0, 0);
  __syncthreads();
  for (int kt = 0; kt < KT; ++kt) {
    const int cur = kt & 1;
    if (kt + 1 < KT) stage(cur ^ 1, kt + 1);
#pragma unroll
    for (int ks = 0; ks < 2; ++ks) {
      bf16x8 af[4], bfr[2];
#pragma unroll
      for (int mi = 0; mi < 4; ++mi) {
        const int row = wm * 64 + mi * 16 + cl;
        af[mi] = *(const bf16x8*)((const char*)As[cur] + row * 128 +
                                  ((2 * (ks * 32 + rowb * 8)) ^ ((row & 7) << 4)));
      }
#pragma unroll
      for (int nj = 0; nj < 2; ++nj) {
        const int row = wn * 32 + nj * 16 + cl;
        bfr[nj] = *(const bf16x8*)((const char*)Bs[cur] + row * 128 +
                                   ((2 * (ks * 32 + rowb * 8)) ^ ((row & 7) << 4)));
      }
#pragma unroll
      for (int mi = 0; mi < 4; ++mi)
#pragma unroll
        for (int nj = 0; nj < 2; ++nj)
          acc[mi][nj] = __builtin_amdgcn_mfma_f32_16x16x32_bf16(af[mi], bfr[nj], acc[mi][nj], 0, 0, 0);
    }
    __syncthreads();
  }
#pragma unroll
  for (int mi = 0; mi < 4; ++mi)
#pragma unroll
    for (int i = 0; i < 4; ++i) {
      const size_t m = m0 + wm * 64 + mi * 16 + rowb * 4 + i;
#pragma unroll
      for (int nj = 0; nj < 2; ++nj)
        C[m * N + n0 + wn * 32 + nj * 16 + cl] = acc[mi][nj][i];
    }
}

// ---------------- fused depthwise conv3x3 + SiLU + headwise q/k/v ----------
// thread = (p, hq): conv for channels 4hq..4hq+3 -> xa; headwise uses the
// same 4 channels (q,k from xa; v from center tap = x_m).
__global__ __launch_bounds__(256) void conv_head_kernel(
    const float* __restrict__ y, const float* __restrict__ cw,
    const float* __restrict__ qw, const float* __restrict__ kw, const float* __restrict__ vw,
    float* __restrict__ xa,
    ushort_t* __restrict__ qg, ushort_t* __restrict__ kg, ushort_t* __restrict__ vg) {
  const int idx = blockIdx.x * 256 + threadIdx.x;   // 8192*72
  const int hq = idx % 72;
  const int p = idx / 72;
  const int c = hq * 4;
  const int xx = p & 31, yy = (p >> 5) & 31, b = p >> 10, s = p & 1023;
  float4 acc = {0.f, 0.f, 0.f, 0.f};
  float4 xmv;
#pragma unroll
  for (int ky = 0; ky < 3; ++ky) {
    const int iy = yy + ky - 1;
    if (iy < 0 || iy >= H_) continue;
#pragma unroll
    for (int kx = 0; kx < 3; ++kx) {
      const int ix = xx + kx - 1;
      if (ix < 0 || ix >= W_) continue;
      const float4 v = *(const float4*)&y[((size_t)((b << 10) + (iy << 5) + ix)) * 576 + c];
      if (ky == 1 && kx == 1) xmv = v;   // center tap = x_m
      const float4 w = *(const float4*)&cw[(ky * 3 + kx) * INNER_ + c];
      acc.x += v.x * w.x; acc.y += v.y * w.y; acc.z += v.z * w.z; acc.w += v.w * w.w;
    }
  }
  float4 xa4;
  xa4.x = acc.x / (1.f + __expf(-acc.x));
  xa4.y = acc.y / (1.f + __expf(-acc.y));
  xa4.z = acc.z / (1.f + __expf(-acc.z));
  xa4.w = acc.w / (1.f + __expf(-acc.w));
  *(float4*)&xa[(size_t)p * INNER_ + c] = xa4;
  // headwise 4x4
  float q[4], k2[4], v[4];
#pragma unroll
  for (int o = 0; o < 4; ++o) {
    const float4 wq = *(const float4*)&qw[hq * 16 + o * 4];
    const float4 wk = *(const float4*)&kw[hq * 16 + o * 4];
    const float4 wv4 = *(const float4*)&vw[hq * 16 + o * 4];
    q[o]  = wq.x * xa4.x + wq.y * xa4.y + wq.z * xa4.z + wq.w * xa4.w;
    k2[o] = wk.x * xa4.x + wk.y * xa4.y + wk.z * xa4.z + wk.w * xa4.w;
    v[o]  = wv4.x * xmv.x + wv4.y * xmv.y + wv4.z * xmv.z + wv4.w * xmv.w;
  }
  const int n = hq / 18, g = hq % 18;
  const int r = (b * 4 + n) * 1024 + s;
  const int swz = (s & 7) << 3;
  ushort4 uq = {f2bf(q[0]), f2bf(q[1]), f2bf(q[2]), f2bf(q[3])};
  ushort4 uk = {f2bf(k2[0]), f2bf(k2[1]), f2bf(k2[2]), f2bf(k2[3])};
  ushort4 uv = {f2bf(v[0]), f2bf(v[1]), f2bf(v[2]), f2bf(v[3])};
  *(ushort4*)&qg[(size_t)r * 128 + ((g * 4) ^ swz)] = uq;
  *(ushort4*)&kg[(size_t)r * 128 + ((g * 4) ^ swz)] = uk;
  *(ushort4*)&vg[(size_t)r * 72 + g * 4] = uv;
}

// ---------------- V transpose -> per-tile swizzled [bn][tt][80x64] ---------
__global__ __launch_bounds__(256) void vtrans_kernel(
    const ushort_t* __restrict__ vg, ushort_t* __restrict__ vtg) {
  __shared__ ushort_t T[64][82];
  const int bn = blockIdx.x >> 4, tt = blockIdx.x & 15;
  const int s0 = tt << 6, tid = threadIdx.x;
  const uint_t* v32 = (const uint_t*)vg;
  for (int i = tid; i < 64 * 36; i += 256) {
    const int rr = i / 36, c2 = i % 36;
    *(uint_t*)&T[rr][c2 * 2] = v32[((size_t)(bn * 1024 + s0 + rr)) * 36 + c2];
  }
  __syncthreads();
  char* outb = (char*)(vtg + ((size_t)(bn * 16 + tt)) * 5120);
  for (int i = tid; i < 80 * 32; i += 256) {
    const int d = i >> 5, m = i & 31;
    uint_t val;
    if (d < 72) val = (uint_t)T[2 * m][d] | ((uint_t)T[2 * m + 1][d] << 16);
    else val = (d == 72) ? 0x3F803F80u : 0u;   // ones row / zero pad
    *(uint_t*)(outb + d * 128 + ((m * 4) ^ ((d & 7) << 4))) = val;
  }
}

// ---------------- gates (swizzled bf16 q/k, plain v) -----------------------
__global__ __launch_bounds__(256) void gates_kernel(
    const ushort_t* __restrict__ qg, const ushort_t* __restrict__ kg, const ushort_t* __restrict__ vg,
    const float* __restrict__ igw, const float* __restrict__ igb,
    const float* __restrict__ fgw, const float* __restrict__ fgb,
    float* __restrict__ ig, float* __restrict__ fg) {
  const int gw = (blockIdx.x * 256 + threadIdx.x) >> 6;  // b*S+s
  const int lane = threadIdx.x & 63;
  const int b = gw >> 10, s = gw & 1023;
  float iacc[4] = {}, facc[4] = {};
  for (int j = lane; j < 864; j += 64) {
    const int part = j / INNER_;
    const int c = j - part * INNER_;
    const int n = c / DHM_, d = c % DHM_;
    const size_t row = (size_t)(b * 4 + n) * 1024 + s;
    ushort_t u;
    if (part == 2)      u = vg[row * 72 + d];
    else {
      const size_t si = row * 128 + (d ^ ((row & 7) << 3));
      u = (part == 0) ? qg[si] : kg[si];
    }
    const float gv = bf2f(u);
#pragma unroll
    for (int nn = 0; nn < 4; ++nn) {
      iacc[nn] += gv * igw[nn * 864 + j];
      facc[nn] += gv * fgw[nn * 864 + j];
    }
  }
#pragma unroll
  for (int off = 32; off >= 1; off >>= 1) {
#pragma unroll
    for (int nn = 0; nn < 4; ++nn) {
      iacc[nn] += __shfl_xor(iacc[nn], off);
      facc[nn] += __shfl_xor(facc[nn], off);
    }
  }
  if (lane == 0) {
#pragma unroll
    for (int nn = 0; nn < 4; ++nn) {
      ig[((size_t)b * NHM_ + nn) * S_ + s] = iacc[nn] + igb[nn];
      fg[((size_t)b * NHM_ + nn) * S_ + s] = facc[nn] + fgb[nn];
    }
  }
}

// ---------------- per-(b,n) scans ------------------------------------------
__global__ __launch_bounds__(256) void scan_kernel(
    const float* __restrict__ fg, const float* __restrict__ ig,
    float* __restrict__ lfc, float* __restrict__ g, float* __restrict__ Mb) {
  __shared__ float sd[256];
  const int bn = blockIdx.x;
  const int tid = threadIdx.x;
  const float* fgp = &fg[(size_t)bn * S_];
  const float* igp = &ig[(size_t)bn * S_];
  float lf[4];
#pragma unroll
  for (int i = 0; i < 4; ++i) {
    const float f = fgp[tid * 4 + i];
    lf[i] = (f >= 0.f) ? -log1pf(expf(-f)) : (f - log1pf(expf(f)));
  }
  float p[4];
  p[0] = lf[0]; p[1] = p[0] + lf[1]; p[2] = p[1] + lf[2]; p[3] = p[2] + lf[3];
  sd[tid] = p[3];
  __syncthreads();
  for (int off = 1; off < 256; off <<= 1) {
    const float v = (tid >= off) ? sd[tid - off] : 0.f;
    __syncthreads();
    sd[tid] += v;
    __syncthreads();
  }
  const float excl = sd[tid] - p[3];
  float l[4];
#pragma unroll
  for (int i = 0; i < 4; ++i) {
    l[i] = excl + p[i];
    lfc[(size_t)bn * S_ + tid * 4 + i] = l[i];
  }
  float gv[4], pm[4];
#pragma unroll
  for (int i = 0; i < 4; ++i) gv[i] = igp[tid * 4 + i] - l[i];
  pm[0] = gv[0];
#pragma unroll
  for (int i = 1; i < 4; ++i) pm[i] = fmaxf(pm[i - 1], gv[i]);
  __syncthreads();
  sd[tid] = pm[3];
  __syncthreads();
  for (int off = 1; off < 256; off <<= 1) {
    const float v = (tid >= off) ? sd[tid - off] : -INFINITY;
    __syncthreads();
    sd[tid] = fmaxf(sd[tid], v);
    __syncthreads();
  }
  const float exclm = (tid > 0) ? sd[tid - 1] : -INFINITY;
#pragma unroll
  for (int i = 0; i < 4; ++i) {
    g[(size_t)bn * S_ + tid * 4 + i] = gv[i];
    Mb[(size_t)bn * S_ + tid * 4 + i] = fmaxf(exclm, pm[i]);
  }
}

// ---------------- mLSTM core + fused LN/skip/silu -> swizzled bf16 hsb -----
__global__ __launch_bounds__(256) void mlstm_mfma(
    const ushort_t* __restrict__ qg, const ushort_t* __restrict__ kg,
    const ushort_t* __restrict__ vtg,
    const float* __restrict__ gb, const float* __restrict__ Mb, const float* __restrict__ lfc,
    const float* __restrict__ xa, const float* __restrict__ y,
    const float* __restrict__ normw, const float* __restrict__ skipw,
    ushort_t* __restrict__ hsb) {
  __shared__ __align__(16) ushort_t Ks[2][64 * 128];
  __shared__ __align__(16) ushort_t Vt[2][80 * 64];
  __shared__ __align__(16) ushort_t Ps[64 * 72];
  __shared__ float gs[1024];
  __shared__ float Ms_s[64], en_s[64];
  // CU-balanced mapping: blocks i and i+256 share a CU (round-robin) and get
  // st pairs (j, 15-j) summing to 17 tiles, with the same bn (L2 reuse).
  const int bi = blockIdx.x;
  const int bn = bi & 31;
  const int j = (bi >> 5) & 7;
  const int st = (bi >> 8) ? (15 - j) : j;
  const int s0 = st << 6;
  const int tid = threadIdx.x, lane = tid & 63, wv = tid >> 6;
  const int cl = lane & 15, rowb = lane >> 4;
  const char* kb = (const char*)(kg + (size_t)bn * 1024 * 128);
  const char* vtb = (const char*)(vtg + (size_t)bn * 16 * 5120);

  auto stage = [&](int buf, int tt) {
    const char* ks = kb + (size_t)tt * (64 * 256);
    const char* vs = vtb + (size_t)tt * 10240;
    for (int u = wv; u < 26; u += 4) {
      if (u < 16) gl16(ks + u * 1024 + lane * 16, (char*)Ks[buf] + u * 1024);
      else        gl16(vs + (u - 16) * 1024 + lane * 16, (char*)Vt[buf] + (u - 16) * 1024);
    }
  };

  // prologue
  stage(0, 0);
  *(float4*)&gs[tid * 4] = *(const float4*)&gb[(size_t)bn * S_ + tid * 4];
  if (tid < 64) {
    const float m = Mb[(size_t)bn * S_ + s0 + tid];
    Ms_s[tid] = m;
    en_s[tid] = __expf(-(lfc[(size_t)bn * S_ + s0 + tid] + m));
  }
  // Q fragments -> registers (swizzled global read, once)
  const int qrow = bn * 1024 + s0 + 16 * wv + cl;
  const ushort_t* qp = qg + (size_t)qrow * 128;
  const int qx = (qrow & 7) << 3;
  bf16x8 qf[3];
#pragma unroll
  for (int kk = 0; kk < 3; ++kk) qf[kk] = *(const bf16x8*)&qp[(kk * 32 + rowb * 8) ^ qx];

  f32x4 accv[5];
#pragma unroll
  for (int n0 = 0; n0 < 5; ++n0) accv[n0] = (f32x4){0.f, 0.f, 0.f, 0.f};
  const float rsc = 0.11785113019775793f;   // 1/sqrt(72)
  const int srl0 = 16 * wv + 4 * rowb;
  __syncthreads();

  // off-diagonal tiles: no causal mask needed
  for (int tt = 0; tt < st; ++tt) {
    const int cur = tt & 1;
    stage(cur ^ 1, tt + 1);
    const int t0 = tt << 6;
    f32x4 qk[4];
#pragma unroll
    for (int n0 = 0; n0 < 4; ++n0) qk[n0] = (f32x4){0.f, 0.f, 0.f, 0.f};
#pragma unroll
    for (int kk = 0; kk < 3; ++kk) {
#pragma unroll
      for (int n0 = 0; n0 < 4; ++n0) {
        const int rl = n0 * 16 + cl;
        const bf16x8 b = *(const bf16x8*)((const char*)Ks[cur] + rl * 256 +
                                          ((2 * (kk * 32 + rowb * 8)) ^ ((rl & 7) << 4)));
        qk[n0] = __builtin_amdgcn_mfma_f32_16x16x32_bf16(qf[kk], b, qk[n0], 0, 0, 0);
      }
    }
#pragma unroll
    for (int n0 = 0; n0 < 4; ++n0) {
      const float gtv = gs[t0 + n0 * 16 + cl];
#pragma unroll
      for (int i = 0; i < 4; ++i) {
        const float w = qk[n0][i] * rsc * __expf(gtv - Ms_s[srl0 + i]);
        Ps[(srl0 + i) * 72 + n0 * 16 + cl] = f2bf(w);
      }
    }
#pragma unroll
    for (int k0 = 0; k0 < 64; k0 += 32) {
      const bf16x8 a = *(const bf16x8*)&Ps[(16 * wv + cl) * 72 + k0 + rowb * 8];
#pragma unroll
      for (int n0 = 0; n0 < 5; ++n0) {
        const int d = n0 * 16 + cl;
        const bf16x8 b = *(const bf16x8*)((const char*)Vt[cur] + d * 128 +
                                          ((2 * (k0 + rowb * 8)) ^ ((d & 7) << 4)));
        accv[n0] = __builtin_amdgcn_mfma_f32_16x16x32_bf16(a, b, accv[n0], 0, 0, 0);
      }
    }
    __syncthreads();
  }
  // diagonal tile (causal mask)
  {
    const int cur = st & 1;
    f32x4 qk[4];
#pragma unroll
    for (int n0 = 0; n0 < 4; ++n0) qk[n0] = (f32x4){0.f, 0.f, 0.f, 0.f};
#pragma unroll
    for (int kk = 0; kk < 3; ++kk) {
#pragma unroll
      for (int n0 = 0; n0 < 4; ++n0) {
        const int rl = n0 * 16 + cl;
        const bf16x8 b = *(const bf16x8*)((const char*)Ks[cur] + rl * 256 +
                                          ((2 * (kk * 32 + rowb * 8)) ^ ((rl & 7) << 4)));
        qk[n0] = __builtin_amdgcn_mfma_f32_16x16x32_bf16(qf[kk], b, qk[n0], 0, 0, 0);
      }
    }
#pragma unroll
    for (int n0 = 0; n0 < 4; ++n0) {
      const int tc = n0 * 16 + cl;
      const float gtv = gs[s0 + tc];
#pragma unroll
      for (int i = 0; i < 4; ++i) {
        const int srl = srl0 + i;
        const float w = (tc <= srl) ? qk[n0][i] * rsc * __expf(gtv - Ms_s[srl]) : 0.f;
        Ps[srl * 72 + n0 * 16 + cl] = f2bf(w);
      }
    }
#pragma unroll
    for (int k0 = 0; k0 < 64; k0 += 32) {
      const bf16x8 a = *(const bf16x8*)&Ps[(16 * wv + cl) * 72 + k0 + rowb * 8];
#pragma unroll
      for (int n0 = 0; n0 < 5; ++n0) {
        const int d = n0 * 16 + cl;
        const bf16x8 b = *(const bf16x8*)((const char*)Vt[cur] + d * 128 +
                                          ((2 * (k0 + rowb * 8)) ^ ((d & 7) << 4)));
        accv[n0] = __builtin_amdgcn_mfma_f32_16x16x32_bf16(a, b, accv[n0], 0, 0, 0);
      }
    }
  }
  // ---- epilogue: normalizer -> LN over d -> +skip*xa -> *silu(z) -> hsb ----
  float inv[4];
#pragma unroll
  for (int i = 0; i < 4; ++i) {
    const float rs = __shfl(accv[4][i], (lane & 48) + 8, 64);
    inv[i] = 1.f / (fmaxf(fabsf(rs), en_s[srl0 + i]) + 1e-6f);
  }
  const int b = bn >> 2, n = bn & 3;
  // per-(n0) weights (d = n0*16+cl < 72)
  float nw[5], sw[5];
#pragma unroll
  for (int n0 = 0; n0 < 5; ++n0) {
    const int d = n0 * 16 + cl;
    nw[n0] = (d < 72) ? normw[n * 72 + d] : 0.f;
    sw[n0] = (d < 72) ? skipw[n * 72 + d] : 0.f;
  }
#pragma unroll
  for (int i = 0; i < 4; ++i) {
    const int srl = srl0 + i;
    const int p = (b << 10) + s0 + srl;
    float hv[5];
#pragma unroll
    for (int n0 = 0; n0 < 5; ++n0) hv[n0] = accv[n0][i] * inv[i];
    // mean over 72 dims (exclude d>=72: n0==4 needs cl<8)
    float hsum = hv[0] + hv[1] + hv[2] + hv[3] + ((cl < 8) ? hv[4] : 0.f);
#pragma unroll
    for (int m = 1; m < 16; m <<= 1) hsum += __shfl_xor(hsum, m);
    const float mean = hsum * (1.f / 72.f);
    float dsq = 0.f;
#pragma unroll
    for (int n0 = 0; n0 < 5; ++n0) {
      const int d = n0 * 16 + cl;
      const float dd = hv[n0] - mean;
      if (d < 72) dsq += dd * dd;
    }
#pragma unroll
    for (int m = 1; m < 16; m <<= 1) dsq += __shfl_xor(dsq, m);
    const float rstd = rsqrtf(dsq * (1.f / 72.f) + 1e-5f);
    const int pswz = (p & 7) << 3;
#pragma unroll
    for (int n0 = 0; n0 < 5; ++n0) {
      const int d = n0 * 16 + cl;
      if (d < 72) {
        const int c = n * 72 + d;
        const float hn = (hv[n0] - mean) * rstd * nw[n0];
        const float xav = xa[(size_t)p * INNER_ + c];
        const float z = y[(size_t)p * 576 + 288 + c];
        const float sz = z / (1.f + __expf(-z));
        hsb[(size_t)p * 320 + (c & ~63) + ((c & 63) ^ pswz)] = f2bf((hn + sw[n0] * xav) * sz);
      }
    }
  }
}

extern "C" void kernel_launch(void* const* d_in, const int* in_sizes, int n_in,
                              void* d_out, int out_size, void* d_ws, size_t ws_size,
                              hipStream_t stream) {
  const float* x           = (const float*)d_in[0];
  const float* proj_up_w   = (const float*)d_in[1];
  const float* q_w         = (const float*)d_in[2];
  const float* k_w         = (const float*)d_in[3];
  const float* v_w         = (const float*)d_in[4];
  const float* conv_w      = (const float*)d_in[5];
  const float* ig_w        = (const float*)d_in[6];
  const float* ig_b        = (const float*)d_in[7];
  const float* fg_w        = (const float*)d_in[8];
  const float* fg_b        = (const float*)d_in[9];
  const float* norm_w      = (const float*)d_in[10];
  const float* skipw       = (const float*)d_in[11];
  const float* proj_down_w = (const float*)d_in[12];
  float* out = (float*)d_out;

  float* ws = (float*)d_ws;
  float* y      = ws;                            // 8192*576
  float* xa     = y      + (size_t)8192 * 576;   // 8192*288
  float* igb_   = xa     + (size_t)8192 * 288;   // 32768
  float* fgb_   = igb_   + 32768;
  float* lfcb   = fgb_   + 32768;
  float* gbuf   = lfcb   + 32768;
  float* Mbuf   = gbuf   + 32768;
  ushort_t* qg  = (ushort_t*)(Mbuf + 32768);                 // 32*1024*128
  ushort_t* kg  = qg  + (size_t)32 * 1024 * 128;
  ushort_t* vg  = kg  + (size_t)32 * 1024 * 128;             // 32*1024*72
  ushort_t* vtg = vg  + (size_t)32 * 1024 * 72;              // 32*16*5120
  ushort_t* xbf = vtg + (size_t)32 * 16 * 5120;              // 8192*192
  ushort_t* wup = xbf + (size_t)8192 * 192;                  // 576*192
  ushort_t* wdn = wup + (size_t)576 * 192;                   // 192*320
  ushort_t* hsb = wdn + (size_t)192 * 320;                   // 8192*320

  // 1. prep: cvts + zero-pads (must precede all producers)
  prep_kernel<<<6312, 256, 0, stream>>>(x, proj_up_w, proj_down_w,
                                        xbf, wup, wdn, hsb, qg, kg);
  // 2. proj_up: y = x @ proj_up_w^T (bf16 MFMA)
  gemm_bf16<3><<<dim3(9, 64), 256, 0, stream>>>(xbf, wup, y, 576);
  // 3. fused conv+silu+headwise -> xa, qg, kg, vg
  conv_head_kernel<<<(8192 * 72) / 256, 256, 0, stream>>>(
      y, conv_w, q_w, k_w, v_w, xa, qg, kg, vg);
  // 4. V transpose -> per-tile swizzled
  vtrans_kernel<<<512, 256, 0, stream>>>(vg, vtg);
  // 5. gates
  gates_kernel<<<8192 / 4, 256, 0, stream>>>(qg, kg, vg, ig_w, ig_b, fg_w, fg_b, igb_, fgb_);
  // 6. scans
  scan_kernel<<<B_ * NHM_, 256, 0, stream>>>(fgb_, igb_, lfcb, gbuf, Mbuf);
  // 7. mLSTM core + fused LN/skip/silu -> hsb
  mlstm_mfma<<<512, 256, 0, stream>>>(qg, kg, vtg, gbuf, Mbuf, lfcb,
                                      xa, y, norm_w, skipw, hsb);
  // 8. proj_down (bf16 MFMA)
  gemm_bf16<5><<<dim3(3, 64), 256, 0, stream>>>(hsb, wdn, out, 192);
}